// Round 3
// baseline (8310.057 us; speedup 1.0000x reference)
//
#include <hip/hip_runtime.h>

#define ZD 256    // Z_NH
#define NE 1000   // NUM_ENTRY
#define NP 1024   // padded entries

typedef __attribute__((ext_vector_type(8))) short short8;
typedef __attribute__((ext_vector_type(4))) float f32x4;

static __device__ __forceinline__ unsigned short f2bf(float x) {
    unsigned u = __float_as_uint(x);
    u = (u + 0x7FFFu + ((u >> 16) & 1u)) >> 16;
    return (unsigned short)u;
}

// exact reference-chain distance: d = fl(fl(hn+en) - 2*fmaf-chain(h,e))
// Chain order is IDENTICAL to the validated scalar version (k ascending,
// single accumulator); float4 loads batch the latency (proven R1 form).
__device__ __attribute__((noinline)) float exact_d(const float* __restrict__ hr,
                                                   const float* __restrict__ er,
                                                   float hn, float ene) {
    float dot = 0.f;
    #pragma unroll 8
    for (int k = 0; k < ZD; k += 4) {
        float4 hv = *(const float4*)(hr + k);
        float4 ev = *(const float4*)(er + k);
        dot = fmaf(hv.x, ev.x, dot);
        dot = fmaf(hv.y, ev.y, dot);
        dot = fmaf(hv.z, ev.z, dot);
        dot = fmaf(hv.w, ev.w, dot);
    }
    return __fsub_rn(__fadd_rn(hn, ene), __fmul_rn(2.0f, dot));
}

// ---------------------------------------------------------------------------
// prep_e: eb (bf16, pre-XOR-swizzled within each 512B row) + en exact pairwise
// ---------------------------------------------------------------------------
__global__ __launch_bounds__(64) void prep_e(const float* __restrict__ emb,
                                             unsigned char* __restrict__ ebB,
                                             float* __restrict__ en) {
    int e = blockIdx.x * 64 + threadIdx.x;
    if (e >= NP) return;
    unsigned base = (unsigned)e * 512u;
    unsigned x = ((unsigned)e & 7u) << 4;
    if (e < NE) {
        const float* row = emb + (size_t)e * ZD;
        for (int k = 0; k < ZD; k += 2) {  // 2k%4==0, pair stays in same dword
            unsigned off = (base + 2u * k) ^ x;
            *(unsigned short*)(ebB + off)     = f2bf(row[k]);
            *(unsigned short*)(ebB + off + 2) = f2bf(row[k + 1]);
        }
        float r[8];
        #pragma unroll
        for (int j = 0; j < 8; ++j) { float v = row[j]; r[j] = __fmul_rn(v, v); }
        for (int i = 8; i < 128; i += 8)
            #pragma unroll
            for (int j = 0; j < 8; ++j) { float v = row[i + j]; r[j] = __fadd_rn(r[j], __fmul_rn(v, v)); }
        float s1 = __fadd_rn(__fadd_rn(__fadd_rn(r[0], r[1]), __fadd_rn(r[2], r[3])),
                             __fadd_rn(__fadd_rn(r[4], r[5]), __fadd_rn(r[6], r[7])));
        #pragma unroll
        for (int j = 0; j < 8; ++j) { float v = row[128 + j]; r[j] = __fmul_rn(v, v); }
        for (int i = 136; i < 256; i += 8)
            #pragma unroll
            for (int j = 0; j < 8; ++j) { float v = row[i + j]; r[j] = __fadd_rn(r[j], __fmul_rn(v, v)); }
        float s2 = __fadd_rn(__fadd_rn(__fadd_rn(r[0], r[1]), __fadd_rn(r[2], r[3])),
                             __fadd_rn(__fadd_rn(r[4], r[5]), __fadd_rn(r[6], r[7])));
        en[e] = __fadd_rn(s1, s2);
    } else {
        for (int k = 0; k < 128; ++k) *(unsigned*)(ebB + base + 4u * k) = 0u;
        en[e] = __builtin_inff();
    }
}

// ---------------------------------------------------------------------------
// prep_h: hb (bf16 rows, stored in out_q region, row stride 512 ushorts) and
// hn (exact numpy-pairwise, stored in out_i region as float bits)
// ---------------------------------------------------------------------------
__global__ __launch_bounds__(256) void prep_h(const float* __restrict__ h,
                                              unsigned short* __restrict__ hb,
                                              float* __restrict__ hn) {
    __shared__ float L[64][257];
    const int t = threadIdx.x;
    const long row0 = (long)blockIdx.x * 64;
    const int kq = (t & 63) * 4;
    const int rq = t >> 6;
    #pragma unroll
    for (int p = 0; p < 16; ++p) {
        int row = p * 4 + rq;
        float4 v = *(const float4*)(h + (row0 + row) * ZD + kq);
        L[row][kq] = v.x; L[row][kq + 1] = v.y; L[row][kq + 2] = v.z; L[row][kq + 3] = v.w;
    }
    __syncthreads();
    #pragma unroll
    for (int p = 0; p < 16; ++p) {
        int row = p * 4 + rq;
        ushort4 o;
        o.x = f2bf(L[row][kq]);     o.y = f2bf(L[row][kq + 1]);
        o.z = f2bf(L[row][kq + 2]); o.w = f2bf(L[row][kq + 3]);
        *(ushort4*)(hb + (row0 + row) * 512 + kq) = o;
    }
    if (t < 64) {
        float r[8];
        #pragma unroll
        for (int j = 0; j < 8; ++j) { float v = L[t][j]; r[j] = __fmul_rn(v, v); }
        for (int i = 8; i < 128; i += 8)
            #pragma unroll
            for (int j = 0; j < 8; ++j) { float v = L[t][i + j]; r[j] = __fadd_rn(r[j], __fmul_rn(v, v)); }
        float s1 = __fadd_rn(__fadd_rn(__fadd_rn(r[0], r[1]), __fadd_rn(r[2], r[3])),
                             __fadd_rn(__fadd_rn(r[4], r[5]), __fadd_rn(r[6], r[7])));
        #pragma unroll
        for (int j = 0; j < 8; ++j) { float v = L[t][128 + j]; r[j] = __fmul_rn(v, v); }
        for (int i = 136; i < 256; i += 8)
            #pragma unroll
            for (int j = 0; j < 8; ++j) { float v = L[t][i + j]; r[j] = __fadd_rn(r[j], __fmul_rn(v, v)); }
        float s2 = __fadd_rn(__fadd_rn(__fadd_rn(r[0], r[1]), __fadd_rn(r[2], r[3])),
                             __fadd_rn(__fadd_rn(r[4], r[5]), __fadd_rn(r[6], r[7])));
        hn[row0 + t] = __fadd_rn(s1, s2);
    }
}

// ---------------------------------------------------------------------------
// main: 16 waves x 16 rows = 256 rows/block (R1 structure, byte-identical
// insert loop), but 64 KB chunks x 8 -> 66 KB LDS -> 2 blocks/CU resident.
// One block's MFMA main loop overlaps the other's staging barrier drain and
// latency-heavy exact-verify epilogue.
// ---------------------------------------------------------------------------
__global__ __launch_bounds__(1024, 8) void vq_main(const float* __restrict__ h,
                                                   const float* __restrict__ emb,
                                                   const unsigned char* __restrict__ ebB,
                                                   const float* __restrict__ en,
                                                   float* out, int M) {
    extern __shared__ char lds[];
    char* BsB = lds;                          // 65536 B swizzled bf16 chunk
    float* en_s = (float*)(lds + 65536);      // 128 floats

    const int t  = threadIdx.x;
    const int lane = t & 63;
    const int wv = t >> 6;                    // 0..15
    const int g  = lane >> 4;                 // 0..3
    const int lg = lane & 15;
    const long rbase = (long)blockIdx.x * 256 + wv * 16;

    const unsigned short* hb = (const unsigned short*)out;    // bf16 h rows
    const float* hnp = out + (size_t)M * ZD;                  // hn values

    // ---- A fragments: row = rbase+lg, k = kt*32 + g*8 .. +8 (consistent f) ----
    short8 afrag[8];
    {
        const unsigned short* hr = hb + (rbase + lg) * 512;
        #pragma unroll
        for (int kt = 0; kt < 8; ++kt)
            afrag[kt] = *(const short8*)(hr + kt * 32 + g * 8);
    }
    float hnr[4], taur[4];
    #pragma unroll
    for (int i = 0; i < 4; ++i) {
        hnr[i] = hnp[rbase + g * 4 + i];
        taur[i] = 1.0e-5f * sqrtf(256.0f * hnr[i]) + 1.0e-3f;
    }

    const float INF = __builtin_inff();
    float bv0[4], bv1[4], bv2[4], bv3[4];
    int   bi0[4], bi1[4], bi2[4], bi3[4];
    #pragma unroll
    for (int i = 0; i < 4; ++i) {
        bv0[i] = INF; bv1[i] = INF; bv2[i] = INF; bv3[i] = INF;
        bi0[i] = 0;   bi1[i] = 0;   bi2[i] = 0;   bi3[i] = 0;
    }

    for (int c = 0; c < 8; ++c) {
        { // stage pre-swizzled 64KB chunk linearly (coalesced, conflict-free)
            const uint4* src = (const uint4*)(ebB + (size_t)c * 65536);
            uint4* dst = (uint4*)BsB;
            #pragma unroll
            for (int p = 0; p < 4; ++p) dst[p * 1024 + t] = src[p * 1024 + t];
        }
        if (t < 32) {
            float4 v = *(const float4*)(en + c * 128 + t * 4);
            *(float4*)(en_s + t * 4) = v;
        }
        __syncthreads();

        for (int nt = 0; nt < 8; ++nt) {
            // two independent 4-deep MFMA chains (approx only; tau covers the
            // summation-order delta, 2*eps ~ 1.5e-4 << tau ~ 3.6e-3)
            f32x4 acc0 = {0.f, 0.f, 0.f, 0.f};
            f32x4 acc1 = {0.f, 0.f, 0.f, 0.f};
            const int nb = nt * 16 + lg;                       // entry in chunk
            const unsigned x = ((unsigned)lg & 7u) << 4;
            const unsigned rowb = (unsigned)nb * 512u;
            #pragma unroll
            for (int kt = 0; kt < 4; ++kt) {
                short8 b0 = *(const short8*)(BsB + ((rowb + (unsigned)kt * 64u + g * 16u) ^ x));
                short8 b1 = *(const short8*)(BsB + ((rowb + (unsigned)(kt + 4) * 64u + g * 16u) ^ x));
                acc0 = __builtin_amdgcn_mfma_f32_16x16x32_bf16(afrag[kt],     b0, acc0, 0, 0, 0);
                acc1 = __builtin_amdgcn_mfma_f32_16x16x32_bf16(afrag[kt + 4], b1, acc1, 0, 0, 0);
            }
            const int eIdx = c * 128 + nb;
            const float ene = en_s[nb];
            #pragma unroll
            for (int i = 0; i < 4; ++i) {
                float dot = __fadd_rn(acc0[i], acc1[i]);
                float d = __fsub_rn(__fadd_rn(hnr[i], ene), __fmul_rn(2.0f, dot));
                if (__any(d < bv3[i])) {
                    bool l3 = d < bv3[i], l2 = d < bv2[i], l1 = d < bv1[i], l0 = d < bv0[i];
                    bv3[i] = l3 ? (l2 ? bv2[i] : d) : bv3[i];
                    bi3[i] = l3 ? (l2 ? bi2[i] : eIdx) : bi3[i];
                    bv2[i] = l2 ? (l1 ? bv1[i] : d) : bv2[i];
                    bi2[i] = l2 ? (l1 ? bi1[i] : eIdx) : bi2[i];
                    bv1[i] = l1 ? (l0 ? bv0[i] : d) : bv1[i];
                    bi1[i] = l1 ? (l0 ? bi0[i] : eIdx) : bi1[i];
                    bv0[i] = l0 ? d : bv0[i];
                    bi0[i] = l0 ? eIdx : bi0[i];
                }
            }
        }
        __syncthreads();
    }

    float* out_q = out;
    float* out_i = out + (size_t)M * ZD;
    float* out_l = out_i + M;

    #pragma unroll 1
    for (int i = 0; i < 4; ++i) {
        const long r = rbase + g * 4 + i;
        const float* hrow = h + (size_t)r * ZD;

        float gmin = bv0[i];
        #pragma unroll
        for (int o = 1; o < 16; o <<= 1) gmin = fminf(gmin, __shfl_xor(gmin, o, 64));
        const float thr = gmin + taur[i];

        unsigned long long bal = __ballot(bv3[i] <= thr);
        const bool flagged = ((bal >> (g * 16)) & 0xFFFFull) != 0ull;

        float bestd = INF;
        int   besti = 0x7FFFFFFF;
        if (!flagged) {
            if (bv0[i] <= thr) {
                float dx = exact_d(hrow, emb + (size_t)bi0[i] * ZD, hnr[i], en[bi0[i]]);
                if (dx < bestd || (dx == bestd && bi0[i] < besti)) { bestd = dx; besti = bi0[i]; }
            }
            if (bv1[i] <= thr) {
                float dx = exact_d(hrow, emb + (size_t)bi1[i] * ZD, hnr[i], en[bi1[i]]);
                if (dx < bestd || (dx == bestd && bi1[i] < besti)) { bestd = dx; besti = bi1[i]; }
            }
            if (bv2[i] <= thr) {
                float dx = exact_d(hrow, emb + (size_t)bi2[i] * ZD, hnr[i], en[bi2[i]]);
                if (dx < bestd || (dx == bestd && bi2[i] < besti)) { bestd = dx; besti = bi2[i]; }
            }
            if (bv3[i] <= thr) {
                float dx = exact_d(hrow, emb + (size_t)bi3[i] * ZD, hnr[i], en[bi3[i]]);
                if (dx < bestd || (dx == bestd && bi3[i] < besti)) { bestd = dx; besti = bi3[i]; }
            }
        } else {
            // exhaustive fallback: two independent chains interleaved per lane
            // (entries e and e+16), float4 loads; evaluation order e < e2 keeps
            // the lowest-index tie-break identical to the serial version.
            for (int e = lg; e < NE; e += 32) {
                const int e2 = e + 16;
                const bool h2 = (e2 < NE);
                const float* er0 = emb + (size_t)e * ZD;
                const float* er1 = emb + (size_t)(h2 ? e2 : e) * ZD;
                float dot0 = 0.f, dot1 = 0.f;
                #pragma unroll 8
                for (int k = 0; k < ZD; k += 4) {
                    float4 hv = *(const float4*)(hrow + k);
                    float4 a = *(const float4*)(er0 + k);
                    float4 b = *(const float4*)(er1 + k);
                    dot0 = fmaf(hv.x, a.x, dot0); dot1 = fmaf(hv.x, b.x, dot1);
                    dot0 = fmaf(hv.y, a.y, dot0); dot1 = fmaf(hv.y, b.y, dot1);
                    dot0 = fmaf(hv.z, a.z, dot0); dot1 = fmaf(hv.z, b.z, dot1);
                    dot0 = fmaf(hv.w, a.w, dot0); dot1 = fmaf(hv.w, b.w, dot1);
                }
                float dx0 = __fsub_rn(__fadd_rn(hnr[i], en[e]), __fmul_rn(2.0f, dot0));
                if (dx0 < bestd || (dx0 == bestd && e < besti)) { bestd = dx0; besti = e; }
                if (h2) {
                    float dx1 = __fsub_rn(__fadd_rn(hnr[i], en[e2]), __fmul_rn(2.0f, dot1));
                    if (dx1 < bestd || (dx1 == bestd && e2 < besti)) { bestd = dx1; besti = e2; }
                }
            }
        }
        #pragma unroll
        for (int o = 1; o < 16; o <<= 1) {
            float ov = __shfl_xor(bestd, o, 64);
            int   oi = __shfl_xor(besti, o, 64);
            if (ov < bestd || (ov == bestd && oi < besti)) { bestd = ov; besti = oi; }
        }

        // epilogue (identical numerics to validated R1/R3 chain)
        const float* erow = emb + (size_t)besti * ZD;
        float csum = 0.0f;
        #pragma unroll
        for (int q4 = 0; q4 < 4; ++q4) {
            int k = lg * 16 + q4 * 4;
            float4 hv = *(const float4*)(hrow + k);
            float4 ev = *(const float4*)(erow + k);
            float dx = __fsub_rn(ev.x, hv.x);
            float dy = __fsub_rn(ev.y, hv.y);
            float dz = __fsub_rn(ev.z, hv.z);
            float dw = __fsub_rn(ev.w, hv.w);
            float4 o;
            o.x = __fadd_rn(hv.x, dx);
            o.y = __fadd_rn(hv.y, dy);
            o.z = __fadd_rn(hv.z, dz);
            o.w = __fadd_rn(hv.w, dw);
            *(float4*)(out_q + (size_t)r * ZD + k) = o;
            csum = fmaf(dx, dx, csum);
            csum = fmaf(dy, dy, csum);
            csum = fmaf(dz, dz, csum);
            csum = fmaf(dw, dw, csum);
        }
        #pragma unroll
        for (int o2 = 1; o2 < 16; o2 <<= 1) csum += __shfl_xor(csum, o2, 64);
        if (lg == 0) {
            float cmean = csum * (1.0f / 256.0f);
            out_i[r] = (float)besti;
            out_l[r] = __fadd_rn(__fmul_rn(cmean, 0.1f), __fmul_rn(cmean, 0.2f));
        }
    }
}

extern "C" void kernel_launch(void* const* d_in, const int* in_sizes, int n_in,
                              void* d_out, int out_size, void* d_ws, size_t ws_size,
                              hipStream_t stream) {
    const float* h   = (const float*)d_in[0];
    const float* emb = (const float*)d_in[1];
    const int M = in_sizes[0] / ZD;   // 131072

    unsigned char* ebB = (unsigned char*)d_ws;               // 512 KB bf16 swizzled
    float* en = (float*)(ebB + (size_t)NP * ZD * 2);         // 4 KB

    float* out = (float*)d_out;
    unsigned short* hb = (unsigned short*)d_out;             // bf16 h in out_q region
    float* hn = out + (size_t)M * ZD;                        // hn in out_i region

    prep_e<<<NP / 64, 64, 0, stream>>>(emb, ebB, en);
    prep_h<<<M / 64, 256, 0, stream>>>(h, hb, hn);

    const size_t lds_bytes = 65536 + 128 * sizeof(float);
    (void)hipFuncSetAttribute((const void*)vq_main,
                              hipFuncAttributeMaxDynamicSharedMemorySize,
                              (int)lds_bytes);
    vq_main<<<M / 256, 1024, lds_bytes, stream>>>(h, emb, ebB, en, out, M);
}

// Round 4
// 1334.300 us; speedup vs baseline: 6.2280x; 6.2280x over previous
//
#include <hip/hip_runtime.h>

#define ZD 256    // Z_NH
#define NE 1000   // NUM_ENTRY
#define NP 1024   // padded entries

typedef __attribute__((ext_vector_type(8))) short short8;
typedef __attribute__((ext_vector_type(4))) float f32x4;

static __device__ __forceinline__ unsigned short f2bf(float x) {
    unsigned u = __float_as_uint(x);
    u = (u + 0x7FFFu + ((u >> 16) & 1u)) >> 16;
    return (unsigned short)u;
}

// exact reference-chain distance: d = fl(fl(hn+en) - 2*fmaf-chain(h,e))
// Chain order is IDENTICAL to the validated scalar version (k ascending,
// single accumulator); float4 loads batch the latency (proven R1 form).
__device__ __attribute__((noinline)) float exact_d(const float* __restrict__ hr,
                                                   const float* __restrict__ er,
                                                   float hn, float ene) {
    float dot = 0.f;
    #pragma unroll 8
    for (int k = 0; k < ZD; k += 4) {
        float4 hv = *(const float4*)(hr + k);
        float4 ev = *(const float4*)(er + k);
        dot = fmaf(hv.x, ev.x, dot);
        dot = fmaf(hv.y, ev.y, dot);
        dot = fmaf(hv.z, ev.z, dot);
        dot = fmaf(hv.w, ev.w, dot);
    }
    return __fsub_rn(__fadd_rn(hn, ene), __fmul_rn(2.0f, dot));
}

// ---------------------------------------------------------------------------
// prep_e: eb (bf16, pre-XOR-swizzled within each 512B row) + en exact pairwise
// ---------------------------------------------------------------------------
__global__ __launch_bounds__(64) void prep_e(const float* __restrict__ emb,
                                             unsigned char* __restrict__ ebB,
                                             float* __restrict__ en) {
    int e = blockIdx.x * 64 + threadIdx.x;
    if (e >= NP) return;
    unsigned base = (unsigned)e * 512u;
    unsigned x = ((unsigned)e & 7u) << 4;
    if (e < NE) {
        const float* row = emb + (size_t)e * ZD;
        for (int k = 0; k < ZD; k += 2) {  // 2k%4==0, pair stays in same dword
            unsigned off = (base + 2u * k) ^ x;
            *(unsigned short*)(ebB + off)     = f2bf(row[k]);
            *(unsigned short*)(ebB + off + 2) = f2bf(row[k + 1]);
        }
        float r[8];
        #pragma unroll
        for (int j = 0; j < 8; ++j) { float v = row[j]; r[j] = __fmul_rn(v, v); }
        for (int i = 8; i < 128; i += 8)
            #pragma unroll
            for (int j = 0; j < 8; ++j) { float v = row[i + j]; r[j] = __fadd_rn(r[j], __fmul_rn(v, v)); }
        float s1 = __fadd_rn(__fadd_rn(__fadd_rn(r[0], r[1]), __fadd_rn(r[2], r[3])),
                             __fadd_rn(__fadd_rn(r[4], r[5]), __fadd_rn(r[6], r[7])));
        #pragma unroll
        for (int j = 0; j < 8; ++j) { float v = row[128 + j]; r[j] = __fmul_rn(v, v); }
        for (int i = 136; i < 256; i += 8)
            #pragma unroll
            for (int j = 0; j < 8; ++j) { float v = row[i + j]; r[j] = __fadd_rn(r[j], __fmul_rn(v, v)); }
        float s2 = __fadd_rn(__fadd_rn(__fadd_rn(r[0], r[1]), __fadd_rn(r[2], r[3])),
                             __fadd_rn(__fadd_rn(r[4], r[5]), __fadd_rn(r[6], r[7])));
        en[e] = __fadd_rn(s1, s2);
    } else {
        for (int k = 0; k < 128; ++k) *(unsigned*)(ebB + base + 4u * k) = 0u;
        en[e] = __builtin_inff();
    }
}

// ---------------------------------------------------------------------------
// prep_h: hb (bf16 rows, stored in out_q region, row stride 512 ushorts) and
// hn (exact numpy-pairwise, stored in out_i region as float bits)
// ---------------------------------------------------------------------------
__global__ __launch_bounds__(256) void prep_h(const float* __restrict__ h,
                                              unsigned short* __restrict__ hb,
                                              float* __restrict__ hn) {
    __shared__ float L[64][257];
    const int t = threadIdx.x;
    const long row0 = (long)blockIdx.x * 64;
    const int kq = (t & 63) * 4;
    const int rq = t >> 6;
    #pragma unroll
    for (int p = 0; p < 16; ++p) {
        int row = p * 4 + rq;
        float4 v = *(const float4*)(h + (row0 + row) * ZD + kq);
        L[row][kq] = v.x; L[row][kq + 1] = v.y; L[row][kq + 2] = v.z; L[row][kq + 3] = v.w;
    }
    __syncthreads();
    #pragma unroll
    for (int p = 0; p < 16; ++p) {
        int row = p * 4 + rq;
        ushort4 o;
        o.x = f2bf(L[row][kq]);     o.y = f2bf(L[row][kq + 1]);
        o.z = f2bf(L[row][kq + 2]); o.w = f2bf(L[row][kq + 3]);
        *(ushort4*)(hb + (row0 + row) * 512 + kq) = o;
    }
    if (t < 64) {
        float r[8];
        #pragma unroll
        for (int j = 0; j < 8; ++j) { float v = L[t][j]; r[j] = __fmul_rn(v, v); }
        for (int i = 8; i < 128; i += 8)
            #pragma unroll
            for (int j = 0; j < 8; ++j) { float v = L[t][i + j]; r[j] = __fadd_rn(r[j], __fmul_rn(v, v)); }
        float s1 = __fadd_rn(__fadd_rn(__fadd_rn(r[0], r[1]), __fadd_rn(r[2], r[3])),
                             __fadd_rn(__fadd_rn(r[4], r[5]), __fadd_rn(r[6], r[7])));
        #pragma unroll
        for (int j = 0; j < 8; ++j) { float v = L[t][128 + j]; r[j] = __fmul_rn(v, v); }
        for (int i = 136; i < 256; i += 8)
            #pragma unroll
            for (int j = 0; j < 8; ++j) { float v = L[t][i + j]; r[j] = __fadd_rn(r[j], __fmul_rn(v, v)); }
        float s2 = __fadd_rn(__fadd_rn(__fadd_rn(r[0], r[1]), __fadd_rn(r[2], r[3])),
                             __fadd_rn(__fadd_rn(r[4], r[5]), __fadd_rn(r[6], r[7])));
        hn[row0 + t] = __fadd_rn(s1, s2);
    }
}

// ---------------------------------------------------------------------------
// main: 16 waves x 16 rows = 256 rows/block (R1 structure, byte-identical
// insert loop), 64 KB chunks x 8 -> 66 KB LDS. launch_bounds(1024,4) gives
// the allocator the proven 128-reg budget (it emits 64 VGPR under it);
// residency is then HW-decided: 64 VGPR x 2048 thr = exactly the CU RF and
// 2 x 66 KB <= 160 KB LDS -> 2 blocks/CU WITHOUT constraining the allocator.
// (R3's (1024,8) forced a 64-reg ceiling -> 32 VGPR + full scratch spill.)
// ---------------------------------------------------------------------------
__global__ __launch_bounds__(1024, 4) void vq_main(const float* __restrict__ h,
                                                   const float* __restrict__ emb,
                                                   const unsigned char* __restrict__ ebB,
                                                   const float* __restrict__ en,
                                                   float* out, int M) {
    extern __shared__ char lds[];
    char* BsB = lds;                          // 65536 B swizzled bf16 chunk
    float* en_s = (float*)(lds + 65536);      // 128 floats

    const int t  = threadIdx.x;
    const int lane = t & 63;
    const int wv = t >> 6;                    // 0..15
    const int g  = lane >> 4;                 // 0..3
    const int lg = lane & 15;
    const long rbase = (long)blockIdx.x * 256 + wv * 16;

    const unsigned short* hb = (const unsigned short*)out;    // bf16 h rows
    const float* hnp = out + (size_t)M * ZD;                  // hn values

    // ---- A fragments: row = rbase+lg, k = kt*32 + g*8 .. +8 (consistent f) ----
    short8 afrag[8];
    {
        const unsigned short* hr = hb + (rbase + lg) * 512;
        #pragma unroll
        for (int kt = 0; kt < 8; ++kt)
            afrag[kt] = *(const short8*)(hr + kt * 32 + g * 8);
    }
    float hnr[4], taur[4];
    #pragma unroll
    for (int i = 0; i < 4; ++i) {
        hnr[i] = hnp[rbase + g * 4 + i];
        taur[i] = 1.0e-5f * sqrtf(256.0f * hnr[i]) + 1.0e-3f;
    }

    const float INF = __builtin_inff();
    float bv0[4], bv1[4], bv2[4], bv3[4];
    int   bi0[4], bi1[4], bi2[4], bi3[4];
    #pragma unroll
    for (int i = 0; i < 4; ++i) {
        bv0[i] = INF; bv1[i] = INF; bv2[i] = INF; bv3[i] = INF;
        bi0[i] = 0;   bi1[i] = 0;   bi2[i] = 0;   bi3[i] = 0;
    }

    for (int c = 0; c < 8; ++c) {
        { // stage pre-swizzled 64KB chunk linearly (coalesced, conflict-free)
            const uint4* src = (const uint4*)(ebB + (size_t)c * 65536);
            uint4* dst = (uint4*)BsB;
            #pragma unroll
            for (int p = 0; p < 4; ++p) dst[p * 1024 + t] = src[p * 1024 + t];
        }
        if (t < 32) {
            float4 v = *(const float4*)(en + c * 128 + t * 4);
            *(float4*)(en_s + t * 4) = v;
        }
        __syncthreads();

        for (int nt = 0; nt < 8; ++nt) {
            // two independent 4-deep MFMA chains (approx only; tau covers the
            // summation-order delta, 2*eps ~ 1.5e-4 << tau ~ 3.6e-3)
            f32x4 acc0 = {0.f, 0.f, 0.f, 0.f};
            f32x4 acc1 = {0.f, 0.f, 0.f, 0.f};
            const int nb = nt * 16 + lg;                       // entry in chunk
            const unsigned x = ((unsigned)lg & 7u) << 4;
            const unsigned rowb = (unsigned)nb * 512u;
            #pragma unroll
            for (int kt = 0; kt < 4; ++kt) {
                short8 b0 = *(const short8*)(BsB + ((rowb + (unsigned)kt * 64u + g * 16u) ^ x));
                short8 b1 = *(const short8*)(BsB + ((rowb + (unsigned)(kt + 4) * 64u + g * 16u) ^ x));
                acc0 = __builtin_amdgcn_mfma_f32_16x16x32_bf16(afrag[kt],     b0, acc0, 0, 0, 0);
                acc1 = __builtin_amdgcn_mfma_f32_16x16x32_bf16(afrag[kt + 4], b1, acc1, 0, 0, 0);
            }
            const int eIdx = c * 128 + nb;
            const float ene = en_s[nb];
            #pragma unroll
            for (int i = 0; i < 4; ++i) {
                float dot = __fadd_rn(acc0[i], acc1[i]);
                float d = __fsub_rn(__fadd_rn(hnr[i], ene), __fmul_rn(2.0f, dot));
                if (__any(d < bv3[i])) {
                    bool l3 = d < bv3[i], l2 = d < bv2[i], l1 = d < bv1[i], l0 = d < bv0[i];
                    bv3[i] = l3 ? (l2 ? bv2[i] : d) : bv3[i];
                    bi3[i] = l3 ? (l2 ? bi2[i] : eIdx) : bi3[i];
                    bv2[i] = l2 ? (l1 ? bv1[i] : d) : bv2[i];
                    bi2[i] = l2 ? (l1 ? bi1[i] : eIdx) : bi2[i];
                    bv1[i] = l1 ? (l0 ? bv0[i] : d) : bv1[i];
                    bi1[i] = l1 ? (l0 ? bi0[i] : eIdx) : bi1[i];
                    bv0[i] = l0 ? d : bv0[i];
                    bi0[i] = l0 ? eIdx : bi0[i];
                }
            }
        }
        __syncthreads();
    }

    float* out_q = out;
    float* out_i = out + (size_t)M * ZD;
    float* out_l = out_i + M;

    #pragma unroll 1
    for (int i = 0; i < 4; ++i) {
        const long r = rbase + g * 4 + i;
        const float* hrow = h + (size_t)r * ZD;

        float gmin = bv0[i];
        #pragma unroll
        for (int o = 1; o < 16; o <<= 1) gmin = fminf(gmin, __shfl_xor(gmin, o, 64));
        const float thr = gmin + taur[i];

        unsigned long long bal = __ballot(bv3[i] <= thr);
        const bool flagged = ((bal >> (g * 16)) & 0xFFFFull) != 0ull;

        float bestd = INF;
        int   besti = 0x7FFFFFFF;
        if (!flagged) {
            if (bv0[i] <= thr) {
                float dx = exact_d(hrow, emb + (size_t)bi0[i] * ZD, hnr[i], en[bi0[i]]);
                if (dx < bestd || (dx == bestd && bi0[i] < besti)) { bestd = dx; besti = bi0[i]; }
            }
            if (bv1[i] <= thr) {
                float dx = exact_d(hrow, emb + (size_t)bi1[i] * ZD, hnr[i], en[bi1[i]]);
                if (dx < bestd || (dx == bestd && bi1[i] < besti)) { bestd = dx; besti = bi1[i]; }
            }
            if (bv2[i] <= thr) {
                float dx = exact_d(hrow, emb + (size_t)bi2[i] * ZD, hnr[i], en[bi2[i]]);
                if (dx < bestd || (dx == bestd && bi2[i] < besti)) { bestd = dx; besti = bi2[i]; }
            }
            if (bv3[i] <= thr) {
                float dx = exact_d(hrow, emb + (size_t)bi3[i] * ZD, hnr[i], en[bi3[i]]);
                if (dx < bestd || (dx == bestd && bi3[i] < besti)) { bestd = dx; besti = bi3[i]; }
            }
        } else {
            // exhaustive fallback: two independent chains interleaved per lane
            // (entries e and e+16), float4 loads; evaluation order e < e2 keeps
            // the lowest-index tie-break identical to the serial version.
            for (int e = lg; e < NE; e += 32) {
                const int e2 = e + 16;
                const bool h2 = (e2 < NE);
                const float* er0 = emb + (size_t)e * ZD;
                const float* er1 = emb + (size_t)(h2 ? e2 : e) * ZD;
                float dot0 = 0.f, dot1 = 0.f;
                #pragma unroll 8
                for (int k = 0; k < ZD; k += 4) {
                    float4 hv = *(const float4*)(hrow + k);
                    float4 a = *(const float4*)(er0 + k);
                    float4 b = *(const float4*)(er1 + k);
                    dot0 = fmaf(hv.x, a.x, dot0); dot1 = fmaf(hv.x, b.x, dot1);
                    dot0 = fmaf(hv.y, a.y, dot0); dot1 = fmaf(hv.y, b.y, dot1);
                    dot0 = fmaf(hv.z, a.z, dot0); dot1 = fmaf(hv.z, b.z, dot1);
                    dot0 = fmaf(hv.w, a.w, dot0); dot1 = fmaf(hv.w, b.w, dot1);
                }
                float dx0 = __fsub_rn(__fadd_rn(hnr[i], en[e]), __fmul_rn(2.0f, dot0));
                if (dx0 < bestd || (dx0 == bestd && e < besti)) { bestd = dx0; besti = e; }
                if (h2) {
                    float dx1 = __fsub_rn(__fadd_rn(hnr[i], en[e2]), __fmul_rn(2.0f, dot1));
                    if (dx1 < bestd || (dx1 == bestd && e2 < besti)) { bestd = dx1; besti = e2; }
                }
            }
        }
        #pragma unroll
        for (int o = 1; o < 16; o <<= 1) {
            float ov = __shfl_xor(bestd, o, 64);
            int   oi = __shfl_xor(besti, o, 64);
            if (ov < bestd || (ov == bestd && oi < besti)) { bestd = ov; besti = oi; }
        }

        // epilogue (identical numerics to validated R1/R3 chain)
        const float* erow = emb + (size_t)besti * ZD;
        float csum = 0.0f;
        #pragma unroll
        for (int q4 = 0; q4 < 4; ++q4) {
            int k = lg * 16 + q4 * 4;
            float4 hv = *(const float4*)(hrow + k);
            float4 ev = *(const float4*)(erow + k);
            float dx = __fsub_rn(ev.x, hv.x);
            float dy = __fsub_rn(ev.y, hv.y);
            float dz = __fsub_rn(ev.z, hv.z);
            float dw = __fsub_rn(ev.w, hv.w);
            float4 o;
            o.x = __fadd_rn(hv.x, dx);
            o.y = __fadd_rn(hv.y, dy);
            o.z = __fadd_rn(hv.z, dz);
            o.w = __fadd_rn(hv.w, dw);
            *(float4*)(out_q + (size_t)r * ZD + k) = o;
            csum = fmaf(dx, dx, csum);
            csum = fmaf(dy, dy, csum);
            csum = fmaf(dz, dz, csum);
            csum = fmaf(dw, dw, csum);
        }
        #pragma unroll
        for (int o2 = 1; o2 < 16; o2 <<= 1) csum += __shfl_xor(csum, o2, 64);
        if (lg == 0) {
            float cmean = csum * (1.0f / 256.0f);
            out_i[r] = (float)besti;
            out_l[r] = __fadd_rn(__fmul_rn(cmean, 0.1f), __fmul_rn(cmean, 0.2f));
        }
    }
}

extern "C" void kernel_launch(void* const* d_in, const int* in_sizes, int n_in,
                              void* d_out, int out_size, void* d_ws, size_t ws_size,
                              hipStream_t stream) {
    const float* h   = (const float*)d_in[0];
    const float* emb = (const float*)d_in[1];
    const int M = in_sizes[0] / ZD;   // 131072

    unsigned char* ebB = (unsigned char*)d_ws;               // 512 KB bf16 swizzled
    float* en = (float*)(ebB + (size_t)NP * ZD * 2);         // 4 KB

    float* out = (float*)d_out;
    unsigned short* hb = (unsigned short*)d_out;             // bf16 h in out_q region
    float* hn = out + (size_t)M * ZD;                        // hn in out_i region

    prep_e<<<NP / 64, 64, 0, stream>>>(emb, ebB, en);
    prep_h<<<M / 64, 256, 0, stream>>>(h, hb, hn);

    const size_t lds_bytes = 65536 + 128 * sizeof(float);
    (void)hipFuncSetAttribute((const void*)vq_main,
                              hipFuncAttributeMaxDynamicSharedMemorySize,
                              (int)lds_bytes);
    vq_main<<<M / 256, 1024, lds_bytes, stream>>>(h, emb, ebB, en, out, M);
}

// Round 5
// 949.176 us; speedup vs baseline: 8.7550x; 1.4057x over previous
//
#include <hip/hip_runtime.h>

#define ZD 256    // Z_NH
#define NE 1000   // NUM_ENTRY
#define NP 1024   // padded entries

typedef __attribute__((ext_vector_type(8))) short short8;
typedef __attribute__((ext_vector_type(4))) float f32x4;

static __device__ __forceinline__ unsigned short f2bf(float x) {
    unsigned u = __float_as_uint(x);
    u = (u + 0x7FFFu + ((u >> 16) & 1u)) >> 16;
    return (unsigned short)u;
}

// exact reference-chain distance for TWO candidates sharing one h-row:
// per-candidate chain order identical to the validated scalar/R1 version
// (k ascending, single accumulator per candidate); the two chains are
// independent so their latency overlaps, and hrow loads are shared.
__device__ __attribute__((noinline)) float2 exact_d2(const float* __restrict__ hr,
                                                     const float* __restrict__ e0,
                                                     const float* __restrict__ e1,
                                                     float hn, float en0, float en1) {
    float d0 = 0.f, d1 = 0.f;
    #pragma unroll 8
    for (int k = 0; k < ZD; k += 4) {
        float4 hv = *(const float4*)(hr + k);
        float4 a = *(const float4*)(e0 + k);
        float4 b = *(const float4*)(e1 + k);
        d0 = fmaf(hv.x, a.x, d0); d1 = fmaf(hv.x, b.x, d1);
        d0 = fmaf(hv.y, a.y, d0); d1 = fmaf(hv.y, b.y, d1);
        d0 = fmaf(hv.z, a.z, d0); d1 = fmaf(hv.z, b.z, d1);
        d0 = fmaf(hv.w, a.w, d0); d1 = fmaf(hv.w, b.w, d1);
    }
    float2 r;
    r.x = __fsub_rn(__fadd_rn(hn, en0), __fmul_rn(2.0f, d0));
    r.y = __fsub_rn(__fadd_rn(hn, en1), __fmul_rn(2.0f, d1));
    return r;
}

// ---------------------------------------------------------------------------
// prep_e: eb (bf16, pre-XOR-swizzled within each 512B row) + en exact pairwise
// ---------------------------------------------------------------------------
__global__ __launch_bounds__(64) void prep_e(const float* __restrict__ emb,
                                             unsigned char* __restrict__ ebB,
                                             float* __restrict__ en) {
    int e = blockIdx.x * 64 + threadIdx.x;
    if (e >= NP) return;
    unsigned base = (unsigned)e * 512u;
    unsigned x = ((unsigned)e & 7u) << 4;
    if (e < NE) {
        const float* row = emb + (size_t)e * ZD;
        for (int k = 0; k < ZD; k += 2) {  // 2k%4==0, pair stays in same dword
            unsigned off = (base + 2u * k) ^ x;
            *(unsigned short*)(ebB + off)     = f2bf(row[k]);
            *(unsigned short*)(ebB + off + 2) = f2bf(row[k + 1]);
        }
        float r[8];
        #pragma unroll
        for (int j = 0; j < 8; ++j) { float v = row[j]; r[j] = __fmul_rn(v, v); }
        for (int i = 8; i < 128; i += 8)
            #pragma unroll
            for (int j = 0; j < 8; ++j) { float v = row[i + j]; r[j] = __fadd_rn(r[j], __fmul_rn(v, v)); }
        float s1 = __fadd_rn(__fadd_rn(__fadd_rn(r[0], r[1]), __fadd_rn(r[2], r[3])),
                             __fadd_rn(__fadd_rn(r[4], r[5]), __fadd_rn(r[6], r[7])));
        #pragma unroll
        for (int j = 0; j < 8; ++j) { float v = row[128 + j]; r[j] = __fmul_rn(v, v); }
        for (int i = 136; i < 256; i += 8)
            #pragma unroll
            for (int j = 0; j < 8; ++j) { float v = row[i + j]; r[j] = __fadd_rn(r[j], __fmul_rn(v, v)); }
        float s2 = __fadd_rn(__fadd_rn(__fadd_rn(r[0], r[1]), __fadd_rn(r[2], r[3])),
                             __fadd_rn(__fadd_rn(r[4], r[5]), __fadd_rn(r[6], r[7])));
        en[e] = __fadd_rn(s1, s2);
    } else {
        for (int k = 0; k < 128; ++k) *(unsigned*)(ebB + base + 4u * k) = 0u;
        en[e] = __builtin_inff();
    }
}

// ---------------------------------------------------------------------------
// prep_h: hb (bf16 rows, stored in out_q region, row stride 512 ushorts) and
// hn (exact numpy-pairwise, stored in out_i region as float bits)
// ---------------------------------------------------------------------------
__global__ __launch_bounds__(256) void prep_h(const float* __restrict__ h,
                                              unsigned short* __restrict__ hb,
                                              float* __restrict__ hn) {
    __shared__ float L[64][257];
    const int t = threadIdx.x;
    const long row0 = (long)blockIdx.x * 64;
    const int kq = (t & 63) * 4;
    const int rq = t >> 6;
    #pragma unroll
    for (int p = 0; p < 16; ++p) {
        int row = p * 4 + rq;
        float4 v = *(const float4*)(h + (row0 + row) * ZD + kq);
        L[row][kq] = v.x; L[row][kq + 1] = v.y; L[row][kq + 2] = v.z; L[row][kq + 3] = v.w;
    }
    __syncthreads();
    #pragma unroll
    for (int p = 0; p < 16; ++p) {
        int row = p * 4 + rq;
        ushort4 o;
        o.x = f2bf(L[row][kq]);     o.y = f2bf(L[row][kq + 1]);
        o.z = f2bf(L[row][kq + 2]); o.w = f2bf(L[row][kq + 3]);
        *(ushort4*)(hb + (row0 + row) * 512 + kq) = o;
    }
    if (t < 64) {
        float r[8];
        #pragma unroll
        for (int j = 0; j < 8; ++j) { float v = L[t][j]; r[j] = __fmul_rn(v, v); }
        for (int i = 8; i < 128; i += 8)
            #pragma unroll
            for (int j = 0; j < 8; ++j) { float v = L[t][i + j]; r[j] = __fadd_rn(r[j], __fmul_rn(v, v)); }
        float s1 = __fadd_rn(__fadd_rn(__fadd_rn(r[0], r[1]), __fadd_rn(r[2], r[3])),
                             __fadd_rn(__fadd_rn(r[4], r[5]), __fadd_rn(r[6], r[7])));
        #pragma unroll
        for (int j = 0; j < 8; ++j) { float v = L[t][128 + j]; r[j] = __fmul_rn(v, v); }
        for (int i = 136; i < 256; i += 8)
            #pragma unroll
            for (int j = 0; j < 8; ++j) { float v = L[t][i + j]; r[j] = __fadd_rn(r[j], __fmul_rn(v, v)); }
        float s2 = __fadd_rn(__fadd_rn(__fadd_rn(r[0], r[1]), __fadd_rn(r[2], r[3])),
                             __fadd_rn(__fadd_rn(r[4], r[5]), __fadd_rn(r[6], r[7])));
        hn[row0 + t] = __fadd_rn(s1, s2);
    }
}

// ---------------------------------------------------------------------------
// main: R1 structure verbatim (16 waves x 16 rows, 128 KB chunks x 4,
// 1 block/CU — the proven-stable operating point). Changes are confined to
// the epilogue: unique-candidate shortcut + pair-interleaved exact verify.
// ---------------------------------------------------------------------------
__global__ __launch_bounds__(1024, 4) void vq_main(const float* __restrict__ h,
                                                   const float* __restrict__ emb,
                                                   const unsigned char* __restrict__ ebB,
                                                   const float* __restrict__ en,
                                                   float* out, int M) {
    extern __shared__ char lds[];
    char* BsB = lds;                          // 131072 B swizzled bf16 chunk
    float* en_s = (float*)(lds + 131072);     // 256 floats

    const int t  = threadIdx.x;
    const int lane = t & 63;
    const int wv = t >> 6;                    // 0..15
    const int g  = lane >> 4;                 // 0..3
    const int lg = lane & 15;
    const long rbase = (long)blockIdx.x * 256 + wv * 16;

    const unsigned short* hb = (const unsigned short*)out;    // bf16 h rows
    const float* hnp = out + (size_t)M * ZD;                  // hn values

    // ---- A fragments: row = rbase+lg, k = kt*32 + g*8 .. +8 (consistent f) ----
    short8 afrag[8];
    {
        const unsigned short* hr = hb + (rbase + lg) * 512;
        #pragma unroll
        for (int kt = 0; kt < 8; ++kt)
            afrag[kt] = *(const short8*)(hr + kt * 32 + g * 8);
    }
    float hnr[4], taur[4];
    #pragma unroll
    for (int i = 0; i < 4; ++i) {
        hnr[i] = hnp[rbase + g * 4 + i];
        taur[i] = 1.0e-5f * sqrtf(256.0f * hnr[i]) + 1.0e-3f;
    }

    const float INF = __builtin_inff();
    float bv0[4], bv1[4], bv2[4], bv3[4];
    int   bi0[4], bi1[4], bi2[4], bi3[4];
    #pragma unroll
    for (int i = 0; i < 4; ++i) {
        bv0[i] = INF; bv1[i] = INF; bv2[i] = INF; bv3[i] = INF;
        bi0[i] = 0;   bi1[i] = 0;   bi2[i] = 0;   bi3[i] = 0;
    }

    for (int c = 0; c < 4; ++c) {
        { // stage pre-swizzled chunk linearly (coalesced, conflict-free)
            const uint4* src = (const uint4*)(ebB + (size_t)c * 131072);
            uint4* dst = (uint4*)BsB;
            #pragma unroll
            for (int p = 0; p < 8; ++p) dst[p * 1024 + t] = src[p * 1024 + t];
        }
        if (t < 64) {
            float4 v = *(const float4*)(en + c * 256 + t * 4);
            *(float4*)(en_s + t * 4) = v;
        }
        __syncthreads();

        for (int nt = 0; nt < 16; ++nt) {
            // two independent 4-deep MFMA chains (approx only; tau covers the
            // summation-order delta, 2*eps ~ 1.5e-4 << tau ~ 3.6e-3)
            f32x4 acc0 = {0.f, 0.f, 0.f, 0.f};
            f32x4 acc1 = {0.f, 0.f, 0.f, 0.f};
            const int nb = nt * 16 + lg;                       // entry in chunk
            const unsigned x = ((unsigned)lg & 7u) << 4;
            const unsigned rowb = (unsigned)nb * 512u;
            #pragma unroll
            for (int kt = 0; kt < 4; ++kt) {
                short8 b0 = *(const short8*)(BsB + ((rowb + (unsigned)kt * 64u + g * 16u) ^ x));
                short8 b1 = *(const short8*)(BsB + ((rowb + (unsigned)(kt + 4) * 64u + g * 16u) ^ x));
                acc0 = __builtin_amdgcn_mfma_f32_16x16x32_bf16(afrag[kt],     b0, acc0, 0, 0, 0);
                acc1 = __builtin_amdgcn_mfma_f32_16x16x32_bf16(afrag[kt + 4], b1, acc1, 0, 0, 0);
            }
            const int eIdx = c * 256 + nb;
            const float ene = en_s[nb];
            #pragma unroll
            for (int i = 0; i < 4; ++i) {
                float dot = __fadd_rn(acc0[i], acc1[i]);
                float d = __fsub_rn(__fadd_rn(hnr[i], ene), __fmul_rn(2.0f, dot));
                if (__any(d < bv3[i])) {
                    bool l3 = d < bv3[i], l2 = d < bv2[i], l1 = d < bv1[i], l0 = d < bv0[i];
                    bv3[i] = l3 ? (l2 ? bv2[i] : d) : bv3[i];
                    bi3[i] = l3 ? (l2 ? bi2[i] : eIdx) : bi3[i];
                    bv2[i] = l2 ? (l1 ? bv1[i] : d) : bv2[i];
                    bi2[i] = l2 ? (l1 ? bi1[i] : eIdx) : bi2[i];
                    bv1[i] = l1 ? (l0 ? bv0[i] : d) : bv1[i];
                    bi1[i] = l1 ? (l0 ? bi0[i] : eIdx) : bi1[i];
                    bv0[i] = l0 ? d : bv0[i];
                    bi0[i] = l0 ? eIdx : bi0[i];
                }
            }
        }
        __syncthreads();
    }

    float* out_q = out;
    float* out_i = out + (size_t)M * ZD;
    float* out_l = out_i + M;

    #pragma unroll 1
    for (int i = 0; i < 4; ++i) {
        const long r = rbase + g * 4 + i;
        const float* hrow = h + (size_t)r * ZD;

        float gmin = bv0[i];
        #pragma unroll
        for (int o = 1; o < 16; o <<= 1) gmin = fminf(gmin, __shfl_xor(gmin, o, 64));
        const float thr = gmin + taur[i];

        unsigned long long bal0 = __ballot(bv0[i] <= thr);
        unsigned long long bal1 = __ballot(bv1[i] <= thr);
        unsigned long long bal3 = __ballot(bv3[i] <= thr);
        const unsigned b0g = (unsigned)(bal0 >> (g * 16)) & 0xFFFFu;
        const unsigned b1g = (unsigned)(bal1 >> (g * 16)) & 0xFFFFu;
        const bool flagged = ((bal3 >> (g * 16)) & 0xFFFFull) != 0ull;
        // Exactly one in-window candidate group-wide: it is provably the
        // argmin (outside entries have exact d > gmin + tau/2 >= candidate's
        // exact d, strictly) -> no exact verification, no reduce needed.
        const bool unique = (__popc(b0g) == 1) && (b1g == 0u);

        int besti;
        if (unique) {
            const int src = g * 16 + (__ffs(b0g) - 1);
            besti = __shfl(bi0[i], src, 64);
        } else {
            float bestd = INF;
            besti = 0x7FFFFFFF;
            if (!flagged) {
                const bool c0 = bv0[i] <= thr, c1 = bv1[i] <= thr;
                const bool c2 = bv2[i] <= thr, c3 = bv3[i] <= thr;
                {
                    float2 dd = exact_d2(hrow, emb + (size_t)bi0[i] * ZD,
                                         emb + (size_t)bi1[i] * ZD,
                                         hnr[i], en[bi0[i]], en[bi1[i]]);
                    if (c0 && (dd.x < bestd || (dd.x == bestd && bi0[i] < besti))) { bestd = dd.x; besti = bi0[i]; }
                    if (c1 && (dd.y < bestd || (dd.y == bestd && bi1[i] < besti))) { bestd = dd.y; besti = bi1[i]; }
                }
                if (c2 | c3) {
                    float2 dd = exact_d2(hrow, emb + (size_t)bi2[i] * ZD,
                                         emb + (size_t)bi3[i] * ZD,
                                         hnr[i], en[bi2[i]], en[bi3[i]]);
                    if (c2 && (dd.x < bestd || (dd.x == bestd && bi2[i] < besti))) { bestd = dd.x; besti = bi2[i]; }
                    if (c3 && (dd.y < bestd || (dd.y == bestd && bi3[i] < besti))) { bestd = dd.y; besti = bi3[i]; }
                }
            } else {
                // exhaustive fallback: two independent chains interleaved per
                // lane (entries e and e+16), float4 loads; evaluation order
                // e < e2 keeps the lowest-index tie-break identical.
                for (int e = lg; e < NE; e += 32) {
                    const int e2 = e + 16;
                    const bool h2 = (e2 < NE);
                    const float* er0 = emb + (size_t)e * ZD;
                    const float* er1 = emb + (size_t)(h2 ? e2 : e) * ZD;
                    float dot0 = 0.f, dot1 = 0.f;
                    #pragma unroll 8
                    for (int k = 0; k < ZD; k += 4) {
                        float4 hv = *(const float4*)(hrow + k);
                        float4 a = *(const float4*)(er0 + k);
                        float4 b = *(const float4*)(er1 + k);
                        dot0 = fmaf(hv.x, a.x, dot0); dot1 = fmaf(hv.x, b.x, dot1);
                        dot0 = fmaf(hv.y, a.y, dot0); dot1 = fmaf(hv.y, b.y, dot1);
                        dot0 = fmaf(hv.z, a.z, dot0); dot1 = fmaf(hv.z, b.z, dot1);
                        dot0 = fmaf(hv.w, a.w, dot0); dot1 = fmaf(hv.w, b.w, dot1);
                    }
                    float dx0 = __fsub_rn(__fadd_rn(hnr[i], en[e]), __fmul_rn(2.0f, dot0));
                    if (dx0 < bestd || (dx0 == bestd && e < besti)) { bestd = dx0; besti = e; }
                    if (h2) {
                        float dx1 = __fsub_rn(__fadd_rn(hnr[i], en[e2]), __fmul_rn(2.0f, dot1));
                        if (dx1 < bestd || (dx1 == bestd && e2 < besti)) { bestd = dx1; besti = e2; }
                    }
                }
            }
            #pragma unroll
            for (int o = 1; o < 16; o <<= 1) {
                float ov = __shfl_xor(bestd, o, 64);
                int   oi = __shfl_xor(besti, o, 64);
                if (ov < bestd || (ov == bestd && oi < besti)) { bestd = ov; besti = oi; }
            }
        }

        // epilogue (identical numerics to validated R1 chain)
        const float* erow = emb + (size_t)besti * ZD;
        float csum = 0.0f;
        #pragma unroll
        for (int q4 = 0; q4 < 4; ++q4) {
            int k = lg * 16 + q4 * 4;
            float4 hv = *(const float4*)(hrow + k);
            float4 ev = *(const float4*)(erow + k);
            float dx = __fsub_rn(ev.x, hv.x);
            float dy = __fsub_rn(ev.y, hv.y);
            float dz = __fsub_rn(ev.z, hv.z);
            float dw = __fsub_rn(ev.w, hv.w);
            float4 o;
            o.x = __fadd_rn(hv.x, dx);
            o.y = __fadd_rn(hv.y, dy);
            o.z = __fadd_rn(hv.z, dz);
            o.w = __fadd_rn(hv.w, dw);
            *(float4*)(out_q + (size_t)r * ZD + k) = o;
            csum = fmaf(dx, dx, csum);
            csum = fmaf(dy, dy, csum);
            csum = fmaf(dz, dz, csum);
            csum = fmaf(dw, dw, csum);
        }
        #pragma unroll
        for (int o2 = 1; o2 < 16; o2 <<= 1) csum += __shfl_xor(csum, o2, 64);
        if (lg == 0) {
            float cmean = csum * (1.0f / 256.0f);
            out_i[r] = (float)besti;
            out_l[r] = __fadd_rn(__fmul_rn(cmean, 0.1f), __fmul_rn(cmean, 0.2f));
        }
    }
}

extern "C" void kernel_launch(void* const* d_in, const int* in_sizes, int n_in,
                              void* d_out, int out_size, void* d_ws, size_t ws_size,
                              hipStream_t stream) {
    const float* h   = (const float*)d_in[0];
    const float* emb = (const float*)d_in[1];
    const int M = in_sizes[0] / ZD;   // 131072

    unsigned char* ebB = (unsigned char*)d_ws;               // 512 KB bf16 swizzled
    float* en = (float*)(ebB + (size_t)NP * ZD * 2);         // 4 KB

    float* out = (float*)d_out;
    unsigned short* hb = (unsigned short*)d_out;             // bf16 h in out_q region
    float* hn = out + (size_t)M * ZD;                        // hn in out_i region

    prep_e<<<NP / 64, 64, 0, stream>>>(emb, ebB, en);
    prep_h<<<M / 64, 256, 0, stream>>>(h, hb, hn);

    const size_t lds_bytes = 131072 + 256 * sizeof(float);
    (void)hipFuncSetAttribute((const void*)vq_main,
                              hipFuncAttributeMaxDynamicSharedMemorySize,
                              (int)lds_bytes);
    vq_main<<<M / 256, 1024, lds_bytes, stream>>>(h, emb, ebB, en, out, M);
}

// Round 6
// 729.399 us; speedup vs baseline: 11.3930x; 1.3013x over previous
//
#include <hip/hip_runtime.h>

#define ZD 256    // Z_NH
#define NE 1000   // NUM_ENTRY
#define NP 1024   // padded entries

typedef __attribute__((ext_vector_type(8))) short short8;
typedef __attribute__((ext_vector_type(4))) float f32x4;

static __device__ __forceinline__ unsigned short f2bf(float x) {
    unsigned u = __float_as_uint(x);
    u = (u + 0x7FFFu + ((u >> 16) & 1u)) >> 16;
    return (unsigned short)u;
}

// exact reference-chain distance: d = fl(fl(hn+en) - 2*fmaf-chain(h,e))
// Chain order IDENTICAL to the validated R1 version (k ascending, single
// accumulator, float4 loads). Do not change numerics.
__device__ __attribute__((noinline)) float exact_d(const float* __restrict__ hr,
                                                   const float* __restrict__ er,
                                                   float hn, float ene) {
    float dot = 0.f;
    #pragma unroll 8
    for (int k = 0; k < ZD; k += 4) {
        float4 hv = *(const float4*)(hr + k);
        float4 ev = *(const float4*)(er + k);
        dot = fmaf(hv.x, ev.x, dot);
        dot = fmaf(hv.y, ev.y, dot);
        dot = fmaf(hv.z, ev.z, dot);
        dot = fmaf(hv.w, ev.w, dot);
    }
    return __fsub_rn(__fadd_rn(hn, ene), __fmul_rn(2.0f, dot));
}

// ---------------------------------------------------------------------------
// prep_e: eb (bf16, pre-XOR-swizzled within each 512B row) + en exact pairwise
// ---------------------------------------------------------------------------
__global__ __launch_bounds__(64) void prep_e(const float* __restrict__ emb,
                                             unsigned char* __restrict__ ebB,
                                             float* __restrict__ en) {
    int e = blockIdx.x * 64 + threadIdx.x;
    if (e >= NP) return;
    unsigned base = (unsigned)e * 512u;
    unsigned x = ((unsigned)e & 7u) << 4;
    if (e < NE) {
        const float* row = emb + (size_t)e * ZD;
        for (int k = 0; k < ZD; k += 2) {  // 2k%4==0, pair stays in same dword
            unsigned off = (base + 2u * k) ^ x;
            *(unsigned short*)(ebB + off)     = f2bf(row[k]);
            *(unsigned short*)(ebB + off + 2) = f2bf(row[k + 1]);
        }
        float r[8];
        #pragma unroll
        for (int j = 0; j < 8; ++j) { float v = row[j]; r[j] = __fmul_rn(v, v); }
        for (int i = 8; i < 128; i += 8)
            #pragma unroll
            for (int j = 0; j < 8; ++j) { float v = row[i + j]; r[j] = __fadd_rn(r[j], __fmul_rn(v, v)); }
        float s1 = __fadd_rn(__fadd_rn(__fadd_rn(r[0], r[1]), __fadd_rn(r[2], r[3])),
                             __fadd_rn(__fadd_rn(r[4], r[5]), __fadd_rn(r[6], r[7])));
        #pragma unroll
        for (int j = 0; j < 8; ++j) { float v = row[128 + j]; r[j] = __fmul_rn(v, v); }
        for (int i = 136; i < 256; i += 8)
            #pragma unroll
            for (int j = 0; j < 8; ++j) { float v = row[i + j]; r[j] = __fadd_rn(r[j], __fmul_rn(v, v)); }
        float s2 = __fadd_rn(__fadd_rn(__fadd_rn(r[0], r[1]), __fadd_rn(r[2], r[3])),
                             __fadd_rn(__fadd_rn(r[4], r[5]), __fadd_rn(r[6], r[7])));
        en[e] = __fadd_rn(s1, s2);
    } else {
        for (int k = 0; k < 128; ++k) *(unsigned*)(ebB + base + 4u * k) = 0u;
        en[e] = __builtin_inff();
    }
}

// ---------------------------------------------------------------------------
// prep_h: hb (bf16 rows, stored in out_q region, row stride 512 ushorts) and
// hn (exact numpy-pairwise, stored in out_i region as float bits)
// ---------------------------------------------------------------------------
__global__ __launch_bounds__(256) void prep_h(const float* __restrict__ h,
                                              unsigned short* __restrict__ hb,
                                              float* __restrict__ hn) {
    __shared__ float L[64][257];
    const int t = threadIdx.x;
    const long row0 = (long)blockIdx.x * 64;
    const int kq = (t & 63) * 4;
    const int rq = t >> 6;
    #pragma unroll
    for (int p = 0; p < 16; ++p) {
        int row = p * 4 + rq;
        float4 v = *(const float4*)(h + (row0 + row) * ZD + kq);
        L[row][kq] = v.x; L[row][kq + 1] = v.y; L[row][kq + 2] = v.z; L[row][kq + 3] = v.w;
    }
    __syncthreads();
    #pragma unroll
    for (int p = 0; p < 16; ++p) {
        int row = p * 4 + rq;
        ushort4 o;
        o.x = f2bf(L[row][kq]);     o.y = f2bf(L[row][kq + 1]);
        o.z = f2bf(L[row][kq + 2]); o.w = f2bf(L[row][kq + 3]);
        *(ushort4*)(hb + (row0 + row) * 512 + kq) = o;
    }
    if (t < 64) {
        float r[8];
        #pragma unroll
        for (int j = 0; j < 8; ++j) { float v = L[t][j]; r[j] = __fmul_rn(v, v); }
        for (int i = 8; i < 128; i += 8)
            #pragma unroll
            for (int j = 0; j < 8; ++j) { float v = L[t][i + j]; r[j] = __fadd_rn(r[j], __fmul_rn(v, v)); }
        float s1 = __fadd_rn(__fadd_rn(__fadd_rn(r[0], r[1]), __fadd_rn(r[2], r[3])),
                             __fadd_rn(__fadd_rn(r[4], r[5]), __fadd_rn(r[6], r[7])));
        #pragma unroll
        for (int j = 0; j < 8; ++j) { float v = L[t][128 + j]; r[j] = __fmul_rn(v, v); }
        for (int i = 136; i < 256; i += 8)
            #pragma unroll
            for (int j = 0; j < 8; ++j) { float v = L[t][i + j]; r[j] = __fadd_rn(r[j], __fmul_rn(v, v)); }
        float s2 = __fadd_rn(__fadd_rn(__fadd_rn(r[0], r[1]), __fadd_rn(r[2], r[3])),
                             __fadd_rn(__fadd_rn(r[4], r[5]), __fadd_rn(r[6], r[7])));
        hn[row0 + t] = __fadd_rn(s1, s2);
    }
}

// ---------------------------------------------------------------------------
// K1 main: R1 structure verbatim (16 waves x 16 rows, 128 KB chunks x 4,
// 1 block/CU). Epilogue REPLACED by a tiny candidate-record writer: per row,
// write [cnt, idx0..idx6] (or cnt=-1 => exhaustive) into the row's own
// out_q slot. hb row r is dead after this wave's afrag load, so the write
// is safe; no exact_d, no h reads, no output writes here.
// ---------------------------------------------------------------------------
__global__ __launch_bounds__(1024, 4) void vq_main(const float* __restrict__ h,
                                                   const float* __restrict__ emb,
                                                   const unsigned char* __restrict__ ebB,
                                                   const float* __restrict__ en,
                                                   float* out, int M) {
    extern __shared__ char lds[];
    char* BsB = lds;                          // 131072 B swizzled bf16 chunk
    float* en_s = (float*)(lds + 131072);     // 256 floats

    const int t  = threadIdx.x;
    const int lane = t & 63;
    const int wv = t >> 6;                    // 0..15
    const int g  = lane >> 4;                 // 0..3
    const int lg = lane & 15;
    const long rbase = (long)blockIdx.x * 256 + wv * 16;

    const unsigned short* hb = (const unsigned short*)out;    // bf16 h rows
    const float* hnp = out + (size_t)M * ZD;                  // hn values

    // ---- A fragments: row = rbase+lg, k = kt*32 + g*8 .. +8 (consistent f) ----
    short8 afrag[8];
    {
        const unsigned short* hr = hb + (rbase + lg) * 512;
        #pragma unroll
        for (int kt = 0; kt < 8; ++kt)
            afrag[kt] = *(const short8*)(hr + kt * 32 + g * 8);
    }
    float hnr[4], taur[4];
    #pragma unroll
    for (int i = 0; i < 4; ++i) {
        hnr[i] = hnp[rbase + g * 4 + i];
        taur[i] = 1.0e-5f * sqrtf(256.0f * hnr[i]) + 1.0e-3f;
    }

    const float INF = __builtin_inff();
    float bv0[4], bv1[4], bv2[4], bv3[4];
    int   bi0[4], bi1[4], bi2[4], bi3[4];
    #pragma unroll
    for (int i = 0; i < 4; ++i) {
        bv0[i] = INF; bv1[i] = INF; bv2[i] = INF; bv3[i] = INF;
        bi0[i] = 0;   bi1[i] = 0;   bi2[i] = 0;   bi3[i] = 0;
    }

    for (int c = 0; c < 4; ++c) {
        { // stage pre-swizzled chunk linearly (coalesced, conflict-free)
            const uint4* src = (const uint4*)(ebB + (size_t)c * 131072);
            uint4* dst = (uint4*)BsB;
            #pragma unroll
            for (int p = 0; p < 8; ++p) dst[p * 1024 + t] = src[p * 1024 + t];
        }
        if (t < 64) {
            float4 v = *(const float4*)(en + c * 256 + t * 4);
            *(float4*)(en_s + t * 4) = v;
        }
        __syncthreads();

        for (int nt = 0; nt < 16; ++nt) {
            // two independent 4-deep MFMA chains (approx only; tau covers the
            // summation-order delta, 2*eps ~ 1.5e-4 << tau ~ 3.6e-3)
            f32x4 acc0 = {0.f, 0.f, 0.f, 0.f};
            f32x4 acc1 = {0.f, 0.f, 0.f, 0.f};
            const int nb = nt * 16 + lg;                       // entry in chunk
            const unsigned x = ((unsigned)lg & 7u) << 4;
            const unsigned rowb = (unsigned)nb * 512u;
            #pragma unroll
            for (int kt = 0; kt < 4; ++kt) {
                short8 b0 = *(const short8*)(BsB + ((rowb + (unsigned)kt * 64u + g * 16u) ^ x));
                short8 b1 = *(const short8*)(BsB + ((rowb + (unsigned)(kt + 4) * 64u + g * 16u) ^ x));
                acc0 = __builtin_amdgcn_mfma_f32_16x16x32_bf16(afrag[kt],     b0, acc0, 0, 0, 0);
                acc1 = __builtin_amdgcn_mfma_f32_16x16x32_bf16(afrag[kt + 4], b1, acc1, 0, 0, 0);
            }
            const int eIdx = c * 256 + nb;
            const float ene = en_s[nb];
            #pragma unroll
            for (int i = 0; i < 4; ++i) {
                float dot = __fadd_rn(acc0[i], acc1[i]);
                float d = __fsub_rn(__fadd_rn(hnr[i], ene), __fmul_rn(2.0f, dot));
                if (__any(d < bv3[i])) {
                    bool l3 = d < bv3[i], l2 = d < bv2[i], l1 = d < bv1[i], l0 = d < bv0[i];
                    bv3[i] = l3 ? (l2 ? bv2[i] : d) : bv3[i];
                    bi3[i] = l3 ? (l2 ? bi2[i] : eIdx) : bi3[i];
                    bv2[i] = l2 ? (l1 ? bv1[i] : d) : bv2[i];
                    bi2[i] = l2 ? (l1 ? bi1[i] : eIdx) : bi2[i];
                    bv1[i] = l1 ? (l0 ? bv0[i] : d) : bv1[i];
                    bi1[i] = l1 ? (l0 ? bi0[i] : eIdx) : bi1[i];
                    bv0[i] = l0 ? d : bv0[i];
                    bi0[i] = l0 ? eIdx : bi0[i];
                }
            }
        }
        __syncthreads();
    }

    // ---- candidate-record writer (replaces the old latency-heavy epilogue) ---
    float* out_q = out;
    #pragma unroll 1
    for (int i = 0; i < 4; ++i) {
        const long r = rbase + g * 4 + i;

        float gmin = bv0[i];
        #pragma unroll
        for (int o = 1; o < 16; o <<= 1) gmin = fminf(gmin, __shfl_xor(gmin, o, 64));
        const float thr = gmin + taur[i];

        unsigned b0 = (unsigned)(__ballot(bv0[i] <= thr) >> (g * 16)) & 0xFFFFu;
        unsigned b1 = (unsigned)(__ballot(bv1[i] <= thr) >> (g * 16)) & 0xFFFFu;
        unsigned b2 = (unsigned)(__ballot(bv2[i] <= thr) >> (g * 16)) & 0xFFFFu;
        unsigned b3 = (unsigned)(__ballot(bv3[i] <= thr) >> (g * 16)) & 0xFFFFu;
        const int cnt = __popc(b0) + __popc(b1) + __popc(b2) + __popc(b3);
        const bool ex = (b3 != 0u) || (cnt > 7);   // 4th-slot hit or overflow

        float* rec = out_q + (size_t)r * ZD;       // hb row r is dead now
        if (lg == 0) rec[0] = ex ? -1.0f : (float)cnt;
        if (!ex) {
            const unsigned mlt = (1u << lg) - 1u;  // lanes below me in group
            int base = 1;
            if (bv0[i] <= thr) rec[base + __popc(b0 & mlt)] = (float)bi0[i];
            base += __popc(b0);
            if (bv1[i] <= thr) rec[base + __popc(b1 & mlt)] = (float)bi1[i];
            base += __popc(b1);
            if (bv2[i] <= thr) rec[base + __popc(b2 & mlt)] = (float)bi2[i];
            // b3 == 0 here, nothing to store for slot 3
        }
    }
}

// ---------------------------------------------------------------------------
// K2 finalize: 16 rows/block x 256 threads, 8192 blocks, no LDS -> full
// occupancy. Reads the candidate record, verifies with the exact fmaf chain
// (each candidate on its OWN lane -> chains overlap; TLP hides latency),
// then writes out_q / out_i / out_l with R1's exact numerics.
// ---------------------------------------------------------------------------
__global__ __launch_bounds__(256) void vq_fin(const float* __restrict__ h,
                                              const float* __restrict__ emb,
                                              const float* __restrict__ en,
                                              float* out, int M) {
    const int t  = threadIdx.x;
    const int lg = t & 15;
    const long r = (long)blockIdx.x * 16 + (t >> 4);

    float* out_q = out;
    float* out_i = out + (size_t)M * ZD;
    float* out_l = out_i + M;

    const float* hrow = h + (size_t)r * ZD;
    const float hn = out_i[r];                 // hn stored here by prep_h
    const float* rec = out_q + (size_t)r * ZD; // record written by vq_main
    const int cnt = (int)rec[0];
    const float INF = __builtin_inff();

    int besti;
    if (cnt == 1) {
        // single in-window candidate: provably the argmin (tau window), no verify
        besti = (int)rec[1];
    } else {
        float bestd = INF;
        besti = 0x7FFFFFFF;
        if (cnt >= 0) {
            // each candidate verified on its own lane; chains run concurrently.
            // (d, idx) lexicographic min-reduce == R1's sequential compare order.
            if (lg < cnt) {
                const int idx = (int)rec[1 + lg];
                bestd = exact_d(hrow, emb + (size_t)idx * ZD, hn, en[idx]);
                besti = idx;
            }
        } else {
            // exhaustive fallback: verbatim R1 (two interleaved chains/lane)
            for (int e = lg; e < NE; e += 32) {
                const int e2 = e + 16;
                const bool h2 = (e2 < NE);
                const float* er0 = emb + (size_t)e * ZD;
                const float* er1 = emb + (size_t)(h2 ? e2 : e) * ZD;
                float dot0 = 0.f, dot1 = 0.f;
                #pragma unroll 8
                for (int k = 0; k < ZD; k += 4) {
                    float4 hv = *(const float4*)(hrow + k);
                    float4 a = *(const float4*)(er0 + k);
                    float4 b = *(const float4*)(er1 + k);
                    dot0 = fmaf(hv.x, a.x, dot0); dot1 = fmaf(hv.x, b.x, dot1);
                    dot0 = fmaf(hv.y, a.y, dot0); dot1 = fmaf(hv.y, b.y, dot1);
                    dot0 = fmaf(hv.z, a.z, dot0); dot1 = fmaf(hv.z, b.z, dot1);
                    dot0 = fmaf(hv.w, a.w, dot0); dot1 = fmaf(hv.w, b.w, dot1);
                }
                float dx0 = __fsub_rn(__fadd_rn(hn, en[e]), __fmul_rn(2.0f, dot0));
                if (dx0 < bestd || (dx0 == bestd && e < besti)) { bestd = dx0; besti = e; }
                if (h2) {
                    float dx1 = __fsub_rn(__fadd_rn(hn, en[e2]), __fmul_rn(2.0f, dot1));
                    if (dx1 < bestd || (dx1 == bestd && e2 < besti)) { bestd = dx1; besti = e2; }
                }
            }
        }
        #pragma unroll
        for (int o = 1; o < 16; o <<= 1) {
            float ov = __shfl_xor(bestd, o, 64);
            int   oi = __shfl_xor(besti, o, 64);
            if (ov < bestd || (ov == bestd && oi < besti)) { bestd = ov; besti = oi; }
        }
    }

    // epilogue (identical numerics to validated R1 chain); out_q stores
    // depend on besti -> record reads complete before the row is overwritten
    const float* erow = emb + (size_t)besti * ZD;
    float csum = 0.0f;
    #pragma unroll
    for (int q4 = 0; q4 < 4; ++q4) {
        int k = lg * 16 + q4 * 4;
        float4 hv = *(const float4*)(hrow + k);
        float4 ev = *(const float4*)(erow + k);
        float dx = __fsub_rn(ev.x, hv.x);
        float dy = __fsub_rn(ev.y, hv.y);
        float dz = __fsub_rn(ev.z, hv.z);
        float dw = __fsub_rn(ev.w, hv.w);
        float4 o;
        o.x = __fadd_rn(hv.x, dx);
        o.y = __fadd_rn(hv.y, dy);
        o.z = __fadd_rn(hv.z, dz);
        o.w = __fadd_rn(hv.w, dw);
        *(float4*)(out_q + (size_t)r * ZD + k) = o;
        csum = fmaf(dx, dx, csum);
        csum = fmaf(dy, dy, csum);
        csum = fmaf(dz, dz, csum);
        csum = fmaf(dw, dw, csum);
    }
    #pragma unroll
    for (int o2 = 1; o2 < 16; o2 <<= 1) csum += __shfl_xor(csum, o2, 64);
    if (lg == 0) {
        float cmean = csum * (1.0f / 256.0f);
        out_i[r] = (float)besti;
        out_l[r] = __fadd_rn(__fmul_rn(cmean, 0.1f), __fmul_rn(cmean, 0.2f));
    }
}

extern "C" void kernel_launch(void* const* d_in, const int* in_sizes, int n_in,
                              void* d_out, int out_size, void* d_ws, size_t ws_size,
                              hipStream_t stream) {
    const float* h   = (const float*)d_in[0];
    const float* emb = (const float*)d_in[1];
    const int M = in_sizes[0] / ZD;   // 131072

    unsigned char* ebB = (unsigned char*)d_ws;               // 512 KB bf16 swizzled
    float* en = (float*)(ebB + (size_t)NP * ZD * 2);         // 4 KB

    float* out = (float*)d_out;
    unsigned short* hb = (unsigned short*)d_out;             // bf16 h in out_q region
    float* hn = out + (size_t)M * ZD;                        // hn in out_i region

    prep_e<<<NP / 64, 64, 0, stream>>>(emb, ebB, en);
    prep_h<<<M / 64, 256, 0, stream>>>(h, hb, hn);

    const size_t lds_bytes = 131072 + 256 * sizeof(float);
    (void)hipFuncSetAttribute((const void*)vq_main,
                              hipFuncAttributeMaxDynamicSharedMemorySize,
                              (int)lds_bytes);
    vq_main<<<M / 256, 1024, lds_bytes, stream>>>(h, emb, ebB, en, out, M);
    vq_fin<<<M / 16, 256, 0, stream>>>(h, emb, en, out, M);
}

// Round 7
// 658.510 us; speedup vs baseline: 12.6195x; 1.1076x over previous
//
#include <hip/hip_runtime.h>

#define ZD 256    // Z_NH
#define NE 1000   // NUM_ENTRY
#define NP 1024   // padded entries

typedef __attribute__((ext_vector_type(8))) short short8;
typedef __attribute__((ext_vector_type(4))) float f32x4;

static __device__ __forceinline__ unsigned short f2bf(float x) {
    unsigned u = __float_as_uint(x);
    u = (u + 0x7FFFu + ((u >> 16) & 1u)) >> 16;
    return (unsigned short)u;
}

// exact reference-chain distance: d = fl(fl(hn+en) - 2*fmaf-chain(h,e))
// Chain order IDENTICAL to the validated R1 version (k ascending, single
// accumulator, float4 loads). Do not change numerics.
__device__ __attribute__((noinline)) float exact_d(const float* __restrict__ hr,
                                                   const float* __restrict__ er,
                                                   float hn, float ene) {
    float dot = 0.f;
    #pragma unroll 8
    for (int k = 0; k < ZD; k += 4) {
        float4 hv = *(const float4*)(hr + k);
        float4 ev = *(const float4*)(er + k);
        dot = fmaf(hv.x, ev.x, dot);
        dot = fmaf(hv.y, ev.y, dot);
        dot = fmaf(hv.z, ev.z, dot);
        dot = fmaf(hv.w, ev.w, dot);
    }
    return __fsub_rn(__fadd_rn(hn, ene), __fmul_rn(2.0f, dot));
}

// exact chains for TWO candidates sharing one h-row (validated in R5: per-
// candidate chain order bit-identical to exact_d; chains independent so
// latency overlaps; hrow loads shared).
__device__ __attribute__((noinline)) float2 exact_d2(const float* __restrict__ hr,
                                                     const float* __restrict__ e0,
                                                     const float* __restrict__ e1,
                                                     float hn, float en0, float en1) {
    float d0 = 0.f, d1 = 0.f;
    #pragma unroll 8
    for (int k = 0; k < ZD; k += 4) {
        float4 hv = *(const float4*)(hr + k);
        float4 a = *(const float4*)(e0 + k);
        float4 b = *(const float4*)(e1 + k);
        d0 = fmaf(hv.x, a.x, d0); d1 = fmaf(hv.x, b.x, d1);
        d0 = fmaf(hv.y, a.y, d0); d1 = fmaf(hv.y, b.y, d1);
        d0 = fmaf(hv.z, a.z, d0); d1 = fmaf(hv.z, b.z, d1);
        d0 = fmaf(hv.w, a.w, d0); d1 = fmaf(hv.w, b.w, d1);
    }
    float2 r;
    r.x = __fsub_rn(__fadd_rn(hn, en0), __fmul_rn(2.0f, d0));
    r.y = __fsub_rn(__fadd_rn(hn, en1), __fmul_rn(2.0f, d1));
    return r;
}

// ---------------------------------------------------------------------------
// prep_e: eb (bf16, pre-XOR-swizzled within each 512B row) + en exact pairwise
// ---------------------------------------------------------------------------
__global__ __launch_bounds__(64) void prep_e(const float* __restrict__ emb,
                                             unsigned char* __restrict__ ebB,
                                             float* __restrict__ en) {
    int e = blockIdx.x * 64 + threadIdx.x;
    if (e >= NP) return;
    unsigned base = (unsigned)e * 512u;
    unsigned x = ((unsigned)e & 7u) << 4;
    if (e < NE) {
        const float* row = emb + (size_t)e * ZD;
        for (int k = 0; k < ZD; k += 2) {  // 2k%4==0, pair stays in same dword
            unsigned off = (base + 2u * k) ^ x;
            *(unsigned short*)(ebB + off)     = f2bf(row[k]);
            *(unsigned short*)(ebB + off + 2) = f2bf(row[k + 1]);
        }
        float r[8];
        #pragma unroll
        for (int j = 0; j < 8; ++j) { float v = row[j]; r[j] = __fmul_rn(v, v); }
        for (int i = 8; i < 128; i += 8)
            #pragma unroll
            for (int j = 0; j < 8; ++j) { float v = row[i + j]; r[j] = __fadd_rn(r[j], __fmul_rn(v, v)); }
        float s1 = __fadd_rn(__fadd_rn(__fadd_rn(r[0], r[1]), __fadd_rn(r[2], r[3])),
                             __fadd_rn(__fadd_rn(r[4], r[5]), __fadd_rn(r[6], r[7])));
        #pragma unroll
        for (int j = 0; j < 8; ++j) { float v = row[128 + j]; r[j] = __fmul_rn(v, v); }
        for (int i = 136; i < 256; i += 8)
            #pragma unroll
            for (int j = 0; j < 8; ++j) { float v = row[i + j]; r[j] = __fadd_rn(r[j], __fmul_rn(v, v)); }
        float s2 = __fadd_rn(__fadd_rn(__fadd_rn(r[0], r[1]), __fadd_rn(r[2], r[3])),
                             __fadd_rn(__fadd_rn(r[4], r[5]), __fadd_rn(r[6], r[7])));
        en[e] = __fadd_rn(s1, s2);
    } else {
        for (int k = 0; k < 128; ++k) *(unsigned*)(ebB + base + 4u * k) = 0u;
        en[e] = __builtin_inff();
    }
}

// ---------------------------------------------------------------------------
// prep_h: hb (bf16 rows, stored in out_q region, row stride 512 ushorts) and
// hn (exact numpy-pairwise, stored in out_i region as float bits)
// ---------------------------------------------------------------------------
__global__ __launch_bounds__(256) void prep_h(const float* __restrict__ h,
                                              unsigned short* __restrict__ hb,
                                              float* __restrict__ hn) {
    __shared__ float L[64][257];
    const int t = threadIdx.x;
    const long row0 = (long)blockIdx.x * 64;
    const int kq = (t & 63) * 4;
    const int rq = t >> 6;
    #pragma unroll
    for (int p = 0; p < 16; ++p) {
        int row = p * 4 + rq;
        float4 v = *(const float4*)(h + (row0 + row) * ZD + kq);
        L[row][kq] = v.x; L[row][kq + 1] = v.y; L[row][kq + 2] = v.z; L[row][kq + 3] = v.w;
    }
    __syncthreads();
    #pragma unroll
    for (int p = 0; p < 16; ++p) {
        int row = p * 4 + rq;
        ushort4 o;
        o.x = f2bf(L[row][kq]);     o.y = f2bf(L[row][kq + 1]);
        o.z = f2bf(L[row][kq + 2]); o.w = f2bf(L[row][kq + 3]);
        *(ushort4*)(hb + (row0 + row) * 512 + kq) = o;
    }
    if (t < 64) {
        float r[8];
        #pragma unroll
        for (int j = 0; j < 8; ++j) { float v = L[t][j]; r[j] = __fmul_rn(v, v); }
        for (int i = 8; i < 128; i += 8)
            #pragma unroll
            for (int j = 0; j < 8; ++j) { float v = L[t][i + j]; r[j] = __fadd_rn(r[j], __fmul_rn(v, v)); }
        float s1 = __fadd_rn(__fadd_rn(__fadd_rn(r[0], r[1]), __fadd_rn(r[2], r[3])),
                             __fadd_rn(__fadd_rn(r[4], r[5]), __fadd_rn(r[6], r[7])));
        #pragma unroll
        for (int j = 0; j < 8; ++j) { float v = L[t][128 + j]; r[j] = __fmul_rn(v, v); }
        for (int i = 136; i < 256; i += 8)
            #pragma unroll
            for (int j = 0; j < 8; ++j) { float v = L[t][i + j]; r[j] = __fadd_rn(r[j], __fmul_rn(v, v)); }
        float s2 = __fadd_rn(__fadd_rn(__fadd_rn(r[0], r[1]), __fadd_rn(r[2], r[3])),
                             __fadd_rn(__fadd_rn(r[4], r[5]), __fadd_rn(r[6], r[7])));
        hn[row0 + t] = __fadd_rn(s1, s2);
    }
}

// ---------------------------------------------------------------------------
// K1 main: unchanged from R6 (proven ~180 us). Writes per-row candidate
// record [cnt, idx0..idx6] (cnt=-1 => exhaustive) into the row's out_q slot.
// ---------------------------------------------------------------------------
__global__ __launch_bounds__(1024, 4) void vq_main(const float* __restrict__ h,
                                                   const float* __restrict__ emb,
                                                   const unsigned char* __restrict__ ebB,
                                                   const float* __restrict__ en,
                                                   float* out, int M) {
    extern __shared__ char lds[];
    char* BsB = lds;                          // 131072 B swizzled bf16 chunk
    float* en_s = (float*)(lds + 131072);     // 256 floats

    const int t  = threadIdx.x;
    const int lane = t & 63;
    const int wv = t >> 6;                    // 0..15
    const int g  = lane >> 4;                 // 0..3
    const int lg = lane & 15;
    const long rbase = (long)blockIdx.x * 256 + wv * 16;

    const unsigned short* hb = (const unsigned short*)out;    // bf16 h rows
    const float* hnp = out + (size_t)M * ZD;                  // hn values

    short8 afrag[8];
    {
        const unsigned short* hr = hb + (rbase + lg) * 512;
        #pragma unroll
        for (int kt = 0; kt < 8; ++kt)
            afrag[kt] = *(const short8*)(hr + kt * 32 + g * 8);
    }
    float hnr[4], taur[4];
    #pragma unroll
    for (int i = 0; i < 4; ++i) {
        hnr[i] = hnp[rbase + g * 4 + i];
        taur[i] = 1.0e-5f * sqrtf(256.0f * hnr[i]) + 1.0e-3f;
    }

    const float INF = __builtin_inff();
    float bv0[4], bv1[4], bv2[4], bv3[4];
    int   bi0[4], bi1[4], bi2[4], bi3[4];
    #pragma unroll
    for (int i = 0; i < 4; ++i) {
        bv0[i] = INF; bv1[i] = INF; bv2[i] = INF; bv3[i] = INF;
        bi0[i] = 0;   bi1[i] = 0;   bi2[i] = 0;   bi3[i] = 0;
    }

    for (int c = 0; c < 4; ++c) {
        {
            const uint4* src = (const uint4*)(ebB + (size_t)c * 131072);
            uint4* dst = (uint4*)BsB;
            #pragma unroll
            for (int p = 0; p < 8; ++p) dst[p * 1024 + t] = src[p * 1024 + t];
        }
        if (t < 64) {
            float4 v = *(const float4*)(en + c * 256 + t * 4);
            *(float4*)(en_s + t * 4) = v;
        }
        __syncthreads();

        for (int nt = 0; nt < 16; ++nt) {
            f32x4 acc0 = {0.f, 0.f, 0.f, 0.f};
            f32x4 acc1 = {0.f, 0.f, 0.f, 0.f};
            const int nb = nt * 16 + lg;
            const unsigned x = ((unsigned)lg & 7u) << 4;
            const unsigned rowb = (unsigned)nb * 512u;
            #pragma unroll
            for (int kt = 0; kt < 4; ++kt) {
                short8 b0 = *(const short8*)(BsB + ((rowb + (unsigned)kt * 64u + g * 16u) ^ x));
                short8 b1 = *(const short8*)(BsB + ((rowb + (unsigned)(kt + 4) * 64u + g * 16u) ^ x));
                acc0 = __builtin_amdgcn_mfma_f32_16x16x32_bf16(afrag[kt],     b0, acc0, 0, 0, 0);
                acc1 = __builtin_amdgcn_mfma_f32_16x16x32_bf16(afrag[kt + 4], b1, acc1, 0, 0, 0);
            }
            const int eIdx = c * 256 + nb;
            const float ene = en_s[nb];
            #pragma unroll
            for (int i = 0; i < 4; ++i) {
                float dot = __fadd_rn(acc0[i], acc1[i]);
                float d = __fsub_rn(__fadd_rn(hnr[i], ene), __fmul_rn(2.0f, dot));
                if (__any(d < bv3[i])) {
                    bool l3 = d < bv3[i], l2 = d < bv2[i], l1 = d < bv1[i], l0 = d < bv0[i];
                    bv3[i] = l3 ? (l2 ? bv2[i] : d) : bv3[i];
                    bi3[i] = l3 ? (l2 ? bi2[i] : eIdx) : bi3[i];
                    bv2[i] = l2 ? (l1 ? bv1[i] : d) : bv2[i];
                    bi2[i] = l2 ? (l1 ? bi1[i] : eIdx) : bi2[i];
                    bv1[i] = l1 ? (l0 ? bv0[i] : d) : bv1[i];
                    bi1[i] = l1 ? (l0 ? bi0[i] : eIdx) : bi1[i];
                    bv0[i] = l0 ? d : bv0[i];
                    bi0[i] = l0 ? eIdx : bi0[i];
                }
            }
        }
        __syncthreads();
    }

    float* out_q = out;
    #pragma unroll 1
    for (int i = 0; i < 4; ++i) {
        const long r = rbase + g * 4 + i;

        float gmin = bv0[i];
        #pragma unroll
        for (int o = 1; o < 16; o <<= 1) gmin = fminf(gmin, __shfl_xor(gmin, o, 64));
        const float thr = gmin + taur[i];

        unsigned b0 = (unsigned)(__ballot(bv0[i] <= thr) >> (g * 16)) & 0xFFFFu;
        unsigned b1 = (unsigned)(__ballot(bv1[i] <= thr) >> (g * 16)) & 0xFFFFu;
        unsigned b2 = (unsigned)(__ballot(bv2[i] <= thr) >> (g * 16)) & 0xFFFFu;
        unsigned b3 = (unsigned)(__ballot(bv3[i] <= thr) >> (g * 16)) & 0xFFFFu;
        const int cnt = __popc(b0) + __popc(b1) + __popc(b2) + __popc(b3);
        const bool ex = (b3 != 0u) || (cnt > 7);

        float* rec = out_q + (size_t)r * ZD;
        if (lg == 0) rec[0] = ex ? -1.0f : (float)cnt;
        if (!ex) {
            const unsigned mlt = (1u << lg) - 1u;
            int base = 1;
            if (bv0[i] <= thr) rec[base + __popc(b0 & mlt)] = (float)bi0[i];
            base += __popc(b0);
            if (bv1[i] <= thr) rec[base + __popc(b1 & mlt)] = (float)bi1[i];
            base += __popc(b1);
            if (bv2[i] <= thr) rec[base + __popc(b2 & mlt)] = (float)bi2[i];
        }
    }
}

// ---------------------------------------------------------------------------
// K2 finalize v2 — built for memory-level parallelism:
//   resolve : one row per LANE (wave owns 64 rows). rec[0..3] = one float4
//             GATHER (64 lines in flight per instruction), hn coalesced.
//   verify  : each lane runs its own row's candidate chains concurrently
//             (pair-interleaved exact_d2, statically unrolled).
//   exhaust : whole-wave, lane-parallel over entries (ultra-rare).
//   stream  : R1's byte-exact epilogue (16-lane groups, same fmaf/csum/
//             shuffle order), besti broadcast via __shfl. No LDS, no barriers.
// ---------------------------------------------------------------------------
__global__ __launch_bounds__(256) void vq_fin(const float* __restrict__ h,
                                              const float* __restrict__ emb,
                                              const float* __restrict__ en,
                                              float* out, int M) {
    const int t    = threadIdx.x;
    const int lane = t & 63;
    const int g    = lane >> 4;
    const int lg   = lane & 15;
    const long W    = (long)blockIdx.x * 4 + (t >> 6);
    const long row0 = W * 64;

    float* out_q = out;
    float* out_i = out + (size_t)M * ZD;
    float* out_l = out_i + M;
    const float INF = __builtin_inff();

    // ---- resolve (64-wide) ----
    const long r_l = row0 + lane;
    const float* rec = out_q + (size_t)r_l * ZD;
    float4 rA = *(const float4*)(rec);        // cnt, i0, i1, i2 — 64-line gather
    const float hn_l = out_i[r_l];            // coalesced 256B load
    int cnt = (int)rA.x;
    int besti = (int)rA.y;                    // exact answer when cnt==1

    // ---- verify (lanes with 2..7 candidates, concurrent across lanes) ----
    if (cnt >= 2) {
        float4 rB = {0.f, 0.f, 0.f, 0.f};
        if (cnt > 3) rB = *(const float4*)(rec + 4);
        const float* hrow = h + (size_t)r_l * ZD;
        const int i0 = (int)rA.y, i1 = (int)rA.z;
        float bestd;
        {
            float2 dd = exact_d2(hrow, emb + (size_t)i0 * ZD, emb + (size_t)i1 * ZD,
                                 hn_l, en[i0], en[i1]);
            bestd = dd.x; besti = i0;
            if (dd.y < bestd || (dd.y == bestd && i1 < besti)) { bestd = dd.y; besti = i1; }
        }
        if (cnt >= 3) {
            const int i2 = (int)rA.w;
            const int i3 = (cnt >= 4) ? (int)rB.x : i2;   // dup pad: idempotent
            float2 dd = exact_d2(hrow, emb + (size_t)i2 * ZD, emb + (size_t)i3 * ZD,
                                 hn_l, en[i2], en[i3]);
            if (dd.x < bestd || (dd.x == bestd && i2 < besti)) { bestd = dd.x; besti = i2; }
            if (dd.y < bestd || (dd.y == bestd && i3 < besti)) { bestd = dd.y; besti = i3; }
        }
        if (cnt >= 5) {
            const int i4 = (int)rB.y;
            const int i5 = (cnt >= 6) ? (int)rB.z : i4;
            float2 dd = exact_d2(hrow, emb + (size_t)i4 * ZD, emb + (size_t)i5 * ZD,
                                 hn_l, en[i4], en[i5]);
            if (dd.x < bestd || (dd.x == bestd && i4 < besti)) { bestd = dd.x; besti = i4; }
            if (dd.y < bestd || (dd.y == bestd && i5 < besti)) { bestd = dd.y; besti = i5; }
        }
        if (cnt >= 7) {
            const int i6 = (int)rB.w;
            float dx = exact_d(hrow, emb + (size_t)i6 * ZD, hn_l, en[i6]);
            if (dx < bestd || (dx == bestd && i6 < besti)) { bestd = dx; besti = i6; }
        }
    }

    // ---- exhaustive rows (P ~ 1e-5): whole-wave, lane-parallel over entries --
    unsigned long long exm = __ballot(cnt < 0);
    while (exm) {
        const int rr = (int)(__ffsll((unsigned long long)exm) - 1);
        exm &= exm - 1;
        const long row = row0 + rr;
        const float hnx = out_i[row];
        const float* hrowx = h + (size_t)row * ZD;
        float bd = INF;
        int   bi = 0x7FFFFFFF;
        for (int e = lane; e < NE; e += 64) {
            float dx = exact_d(hrowx, emb + (size_t)e * ZD, hnx, en[e]);
            if (dx < bd || (dx == bd && e < bi)) { bd = dx; bi = e; }
        }
        #pragma unroll
        for (int o = 1; o < 64; o <<= 1) {
            float ov = __shfl_xor(bd, o, 64);
            int   oi = __shfl_xor(bi, o, 64);
            if (ov < bd || (ov == bd && oi < bi)) { bd = ov; bi = oi; }
        }
        if (lane == rr) besti = bi;
    }

    // ---- stream: R1's byte-exact epilogue, 4 rows per iteration ----
    #pragma unroll 1
    for (int rr4 = 0; rr4 < 16; ++rr4) {
        const long r = row0 + rr4 * 4 + g;
        const int b = __shfl(besti, rr4 * 4 + g, 64);
        const float* hrow = h + (size_t)r * ZD;
        const float* erow = emb + (size_t)b * ZD;
        float csum = 0.0f;
        #pragma unroll
        for (int q4 = 0; q4 < 4; ++q4) {
            int k = lg * 16 + q4 * 4;
            float4 hv = *(const float4*)(hrow + k);
            float4 ev = *(const float4*)(erow + k);
            float dx = __fsub_rn(ev.x, hv.x);
            float dy = __fsub_rn(ev.y, hv.y);
            float dz = __fsub_rn(ev.z, hv.z);
            float dw = __fsub_rn(ev.w, hv.w);
            float4 o;
            o.x = __fadd_rn(hv.x, dx);
            o.y = __fadd_rn(hv.y, dy);
            o.z = __fadd_rn(hv.z, dz);
            o.w = __fadd_rn(hv.w, dw);
            *(float4*)(out_q + (size_t)r * ZD + k) = o;
            csum = fmaf(dx, dx, csum);
            csum = fmaf(dy, dy, csum);
            csum = fmaf(dz, dz, csum);
            csum = fmaf(dw, dw, csum);
        }
        #pragma unroll
        for (int o2 = 1; o2 < 16; o2 <<= 1) csum += __shfl_xor(csum, o2, 64);
        if (lg == 0) {
            float cmean = csum * (1.0f / 256.0f);
            out_i[r] = (float)b;
            out_l[r] = __fadd_rn(__fmul_rn(cmean, 0.1f), __fmul_rn(cmean, 0.2f));
        }
    }
}

extern "C" void kernel_launch(void* const* d_in, const int* in_sizes, int n_in,
                              void* d_out, int out_size, void* d_ws, size_t ws_size,
                              hipStream_t stream) {
    const float* h   = (const float*)d_in[0];
    const float* emb = (const float*)d_in[1];
    const int M = in_sizes[0] / ZD;   // 131072

    unsigned char* ebB = (unsigned char*)d_ws;               // 512 KB bf16 swizzled
    float* en = (float*)(ebB + (size_t)NP * ZD * 2);         // 4 KB

    float* out = (float*)d_out;
    unsigned short* hb = (unsigned short*)d_out;             // bf16 h in out_q region
    float* hn = out + (size_t)M * ZD;                        // hn in out_i region

    prep_e<<<NP / 64, 64, 0, stream>>>(emb, ebB, en);
    prep_h<<<M / 64, 256, 0, stream>>>(h, hb, hn);

    const size_t lds_bytes = 131072 + 256 * sizeof(float);
    (void)hipFuncSetAttribute((const void*)vq_main,
                              hipFuncAttributeMaxDynamicSharedMemorySize,
                              (int)lds_bytes);
    vq_main<<<M / 256, 1024, lds_bytes, stream>>>(h, emb, ebB, en, out, M);
    vq_fin<<<M / 256, 256, 0, stream>>>(h, emb, en, out, M);   // 512 blocks, 64 rows/wave
}

// Round 8
// 600.906 us; speedup vs baseline: 13.8292x; 1.0959x over previous
//
#include <hip/hip_runtime.h>

#define ZD 256    // Z_NH
#define NE 1000   // NUM_ENTRY
#define NP 1024   // padded entries

typedef __attribute__((ext_vector_type(8))) short short8;
typedef __attribute__((ext_vector_type(4))) float f32x4;

static __device__ __forceinline__ unsigned short f2bf(float x) {
    unsigned u = __float_as_uint(x);
    u = (u + 0x7FFFu + ((u >> 16) & 1u)) >> 16;
    return (unsigned short)u;
}

// exact reference-chain distance: d = fl(fl(hn+en) - 2*fmaf-chain(h,e))
// Chain order IDENTICAL to the validated R1 version (k ascending, single
// accumulator, float4 loads). Do not change numerics.
__device__ __attribute__((noinline)) float exact_d(const float* __restrict__ hr,
                                                   const float* __restrict__ er,
                                                   float hn, float ene) {
    float dot = 0.f;
    #pragma unroll 8
    for (int k = 0; k < ZD; k += 4) {
        float4 hv = *(const float4*)(hr + k);
        float4 ev = *(const float4*)(er + k);
        dot = fmaf(hv.x, ev.x, dot);
        dot = fmaf(hv.y, ev.y, dot);
        dot = fmaf(hv.z, ev.z, dot);
        dot = fmaf(hv.w, ev.w, dot);
    }
    return __fsub_rn(__fadd_rn(hn, ene), __fmul_rn(2.0f, dot));
}

// exact chains for TWO candidates sharing one h-row (validated R5/R7: per-
// candidate chain order bit-identical to exact_d; chains independent so
// latency overlaps; hrow loads shared).
__device__ __attribute__((noinline)) float2 exact_d2(const float* __restrict__ hr,
                                                     const float* __restrict__ e0,
                                                     const float* __restrict__ e1,
                                                     float hn, float en0, float en1) {
    float d0 = 0.f, d1 = 0.f;
    #pragma unroll 8
    for (int k = 0; k < ZD; k += 4) {
        float4 hv = *(const float4*)(hr + k);
        float4 a = *(const float4*)(e0 + k);
        float4 b = *(const float4*)(e1 + k);
        d0 = fmaf(hv.x, a.x, d0); d1 = fmaf(hv.x, b.x, d1);
        d0 = fmaf(hv.y, a.y, d0); d1 = fmaf(hv.y, b.y, d1);
        d0 = fmaf(hv.z, a.z, d0); d1 = fmaf(hv.z, b.z, d1);
        d0 = fmaf(hv.w, a.w, d0); d1 = fmaf(hv.w, b.w, d1);
    }
    float2 r;
    r.x = __fsub_rn(__fadd_rn(hn, en0), __fmul_rn(2.0f, d0));
    r.y = __fsub_rn(__fadd_rn(hn, en1), __fmul_rn(2.0f, d1));
    return r;
}

// ---------------------------------------------------------------------------
// prep_e: eb (bf16, pre-XOR-swizzled within each 512B row) + en exact pairwise
// ---------------------------------------------------------------------------
__global__ __launch_bounds__(64) void prep_e(const float* __restrict__ emb,
                                             unsigned char* __restrict__ ebB,
                                             float* __restrict__ en) {
    int e = blockIdx.x * 64 + threadIdx.x;
    if (e >= NP) return;
    unsigned base = (unsigned)e * 512u;
    unsigned x = ((unsigned)e & 7u) << 4;
    if (e < NE) {
        const float* row = emb + (size_t)e * ZD;
        for (int k = 0; k < ZD; k += 2) {  // 2k%4==0, pair stays in same dword
            unsigned off = (base + 2u * k) ^ x;
            *(unsigned short*)(ebB + off)     = f2bf(row[k]);
            *(unsigned short*)(ebB + off + 2) = f2bf(row[k + 1]);
        }
        float r[8];
        #pragma unroll
        for (int j = 0; j < 8; ++j) { float v = row[j]; r[j] = __fmul_rn(v, v); }
        for (int i = 8; i < 128; i += 8)
            #pragma unroll
            for (int j = 0; j < 8; ++j) { float v = row[i + j]; r[j] = __fadd_rn(r[j], __fmul_rn(v, v)); }
        float s1 = __fadd_rn(__fadd_rn(__fadd_rn(r[0], r[1]), __fadd_rn(r[2], r[3])),
                             __fadd_rn(__fadd_rn(r[4], r[5]), __fadd_rn(r[6], r[7])));
        #pragma unroll
        for (int j = 0; j < 8; ++j) { float v = row[128 + j]; r[j] = __fmul_rn(v, v); }
        for (int i = 136; i < 256; i += 8)
            #pragma unroll
            for (int j = 0; j < 8; ++j) { float v = row[i + j]; r[j] = __fadd_rn(r[j], __fmul_rn(v, v)); }
        float s2 = __fadd_rn(__fadd_rn(__fadd_rn(r[0], r[1]), __fadd_rn(r[2], r[3])),
                             __fadd_rn(__fadd_rn(r[4], r[5]), __fadd_rn(r[6], r[7])));
        en[e] = __fadd_rn(s1, s2);
    } else {
        for (int k = 0; k < 128; ++k) *(unsigned*)(ebB + base + 4u * k) = 0u;
        en[e] = __builtin_inff();
    }
}

// ---------------------------------------------------------------------------
// prep_h: hb (bf16 rows, stored in out_q region, row stride 512 ushorts) and
// hn (exact numpy-pairwise, stored in out_i region as float bits)
// ---------------------------------------------------------------------------
__global__ __launch_bounds__(256) void prep_h(const float* __restrict__ h,
                                              unsigned short* __restrict__ hb,
                                              float* __restrict__ hn) {
    __shared__ float L[64][257];
    const int t = threadIdx.x;
    const long row0 = (long)blockIdx.x * 64;
    const int kq = (t & 63) * 4;
    const int rq = t >> 6;
    #pragma unroll
    for (int p = 0; p < 16; ++p) {
        int row = p * 4 + rq;
        float4 v = *(const float4*)(h + (row0 + row) * ZD + kq);
        L[row][kq] = v.x; L[row][kq + 1] = v.y; L[row][kq + 2] = v.z; L[row][kq + 3] = v.w;
    }
    __syncthreads();
    #pragma unroll
    for (int p = 0; p < 16; ++p) {
        int row = p * 4 + rq;
        ushort4 o;
        o.x = f2bf(L[row][kq]);     o.y = f2bf(L[row][kq + 1]);
        o.z = f2bf(L[row][kq + 2]); o.w = f2bf(L[row][kq + 3]);
        *(ushort4*)(hb + (row0 + row) * 512 + kq) = o;
    }
    if (t < 64) {
        float r[8];
        #pragma unroll
        for (int j = 0; j < 8; ++j) { float v = L[t][j]; r[j] = __fmul_rn(v, v); }
        for (int i = 8; i < 128; i += 8)
            #pragma unroll
            for (int j = 0; j < 8; ++j) { float v = L[t][i + j]; r[j] = __fadd_rn(r[j], __fmul_rn(v, v)); }
        float s1 = __fadd_rn(__fadd_rn(__fadd_rn(r[0], r[1]), __fadd_rn(r[2], r[3])),
                             __fadd_rn(__fadd_rn(r[4], r[5]), __fadd_rn(r[6], r[7])));
        #pragma unroll
        for (int j = 0; j < 8; ++j) { float v = L[t][128 + j]; r[j] = __fmul_rn(v, v); }
        for (int i = 136; i < 256; i += 8)
            #pragma unroll
            for (int j = 0; j < 8; ++j) { float v = L[t][i + j]; r[j] = __fadd_rn(r[j], __fmul_rn(v, v)); }
        float s2 = __fadd_rn(__fadd_rn(__fadd_rn(r[0], r[1]), __fadd_rn(r[2], r[3])),
                             __fadd_rn(__fadd_rn(r[4], r[5]), __fadd_rn(r[6], r[7])));
        hn[row0 + t] = __fadd_rn(s1, s2);
    }
}

// ---------------------------------------------------------------------------
// K1 main: unchanged (proven ~180 us). Writes per-row candidate record
// [cnt, idx0..idx6] (cnt=-1 => exhaustive) into the row's out_q slot.
// ---------------------------------------------------------------------------
__global__ __launch_bounds__(1024, 4) void vq_main(const float* __restrict__ h,
                                                   const float* __restrict__ emb,
                                                   const unsigned char* __restrict__ ebB,
                                                   const float* __restrict__ en,
                                                   float* out, int M) {
    extern __shared__ char lds[];
    char* BsB = lds;                          // 131072 B swizzled bf16 chunk
    float* en_s = (float*)(lds + 131072);     // 256 floats

    const int t  = threadIdx.x;
    const int lane = t & 63;
    const int wv = t >> 6;                    // 0..15
    const int g  = lane >> 4;                 // 0..3
    const int lg = lane & 15;
    const long rbase = (long)blockIdx.x * 256 + wv * 16;

    const unsigned short* hb = (const unsigned short*)out;    // bf16 h rows
    const float* hnp = out + (size_t)M * ZD;                  // hn values

    short8 afrag[8];
    {
        const unsigned short* hr = hb + (rbase + lg) * 512;
        #pragma unroll
        for (int kt = 0; kt < 8; ++kt)
            afrag[kt] = *(const short8*)(hr + kt * 32 + g * 8);
    }
    float hnr[4], taur[4];
    #pragma unroll
    for (int i = 0; i < 4; ++i) {
        hnr[i] = hnp[rbase + g * 4 + i];
        taur[i] = 1.0e-5f * sqrtf(256.0f * hnr[i]) + 1.0e-3f;
    }

    const float INF = __builtin_inff();
    float bv0[4], bv1[4], bv2[4], bv3[4];
    int   bi0[4], bi1[4], bi2[4], bi3[4];
    #pragma unroll
    for (int i = 0; i < 4; ++i) {
        bv0[i] = INF; bv1[i] = INF; bv2[i] = INF; bv3[i] = INF;
        bi0[i] = 0;   bi1[i] = 0;   bi2[i] = 0;   bi3[i] = 0;
    }

    for (int c = 0; c < 4; ++c) {
        {
            const uint4* src = (const uint4*)(ebB + (size_t)c * 131072);
            uint4* dst = (uint4*)BsB;
            #pragma unroll
            for (int p = 0; p < 8; ++p) dst[p * 1024 + t] = src[p * 1024 + t];
        }
        if (t < 64) {
            float4 v = *(const float4*)(en + c * 256 + t * 4);
            *(float4*)(en_s + t * 4) = v;
        }
        __syncthreads();

        for (int nt = 0; nt < 16; ++nt) {
            f32x4 acc0 = {0.f, 0.f, 0.f, 0.f};
            f32x4 acc1 = {0.f, 0.f, 0.f, 0.f};
            const int nb = nt * 16 + lg;
            const unsigned x = ((unsigned)lg & 7u) << 4;
            const unsigned rowb = (unsigned)nb * 512u;
            #pragma unroll
            for (int kt = 0; kt < 4; ++kt) {
                short8 b0 = *(const short8*)(BsB + ((rowb + (unsigned)kt * 64u + g * 16u) ^ x));
                short8 b1 = *(const short8*)(BsB + ((rowb + (unsigned)(kt + 4) * 64u + g * 16u) ^ x));
                acc0 = __builtin_amdgcn_mfma_f32_16x16x32_bf16(afrag[kt],     b0, acc0, 0, 0, 0);
                acc1 = __builtin_amdgcn_mfma_f32_16x16x32_bf16(afrag[kt + 4], b1, acc1, 0, 0, 0);
            }
            const int eIdx = c * 256 + nb;
            const float ene = en_s[nb];
            #pragma unroll
            for (int i = 0; i < 4; ++i) {
                float dot = __fadd_rn(acc0[i], acc1[i]);
                float d = __fsub_rn(__fadd_rn(hnr[i], ene), __fmul_rn(2.0f, dot));
                if (__any(d < bv3[i])) {
                    bool l3 = d < bv3[i], l2 = d < bv2[i], l1 = d < bv1[i], l0 = d < bv0[i];
                    bv3[i] = l3 ? (l2 ? bv2[i] : d) : bv3[i];
                    bi3[i] = l3 ? (l2 ? bi2[i] : eIdx) : bi3[i];
                    bv2[i] = l2 ? (l1 ? bv1[i] : d) : bv2[i];
                    bi2[i] = l2 ? (l1 ? bi1[i] : eIdx) : bi2[i];
                    bv1[i] = l1 ? (l0 ? bv0[i] : d) : bv1[i];
                    bi1[i] = l1 ? (l0 ? bi0[i] : eIdx) : bi1[i];
                    bv0[i] = l0 ? d : bv0[i];
                    bi0[i] = l0 ? eIdx : bi0[i];
                }
            }
        }
        __syncthreads();
    }

    float* out_q = out;
    #pragma unroll 1
    for (int i = 0; i < 4; ++i) {
        const long r = rbase + g * 4 + i;

        float gmin = bv0[i];
        #pragma unroll
        for (int o = 1; o < 16; o <<= 1) gmin = fminf(gmin, __shfl_xor(gmin, o, 64));
        const float thr = gmin + taur[i];

        unsigned b0 = (unsigned)(__ballot(bv0[i] <= thr) >> (g * 16)) & 0xFFFFu;
        unsigned b1 = (unsigned)(__ballot(bv1[i] <= thr) >> (g * 16)) & 0xFFFFu;
        unsigned b2 = (unsigned)(__ballot(bv2[i] <= thr) >> (g * 16)) & 0xFFFFu;
        unsigned b3 = (unsigned)(__ballot(bv3[i] <= thr) >> (g * 16)) & 0xFFFFu;
        const int cnt = __popc(b0) + __popc(b1) + __popc(b2) + __popc(b3);
        const bool ex = (b3 != 0u) || (cnt > 7);

        float* rec = out_q + (size_t)r * ZD;
        if (lg == 0) rec[0] = ex ? -1.0f : (float)cnt;
        if (!ex) {
            const unsigned mlt = (1u << lg) - 1u;
            int base = 1;
            if (bv0[i] <= thr) rec[base + __popc(b0 & mlt)] = (float)bi0[i];
            base += __popc(b0);
            if (bv1[i] <= thr) rec[base + __popc(b1 & mlt)] = (float)bi1[i];
            base += __popc(b1);
            if (bv2[i] <= thr) rec[base + __popc(b2 & mlt)] = (float)bi2[i];
        }
    }
}

// ---------------------------------------------------------------------------
// K2a resolve: 16 rows/wave, 4 lanes per row -> 8192 waves (4x R7's TLP),
// <=2 serial verify chains per lane (vs <=4). Lane c of a row verifies
// candidates c and c+4; 4-lane lexicographic (d,idx) reduce == R1's
// sequential compare. besti written (as float) to out_l[r]; vq_stream
// (next kernel on the stream) consumes it.
// ---------------------------------------------------------------------------
__global__ __launch_bounds__(256) void vq_resolve(const float* __restrict__ h,
                                                  const float* __restrict__ emb,
                                                  const float* __restrict__ en,
                                                  float* out, int M) {
    const int t    = threadIdx.x;
    const int lane = t & 63;
    const int wv   = t >> 6;          // 0..3
    const int rr   = lane >> 2;       // row within wave 0..15
    const int c    = lane & 3;        // candidate slot 0..3
    const long row0 = ((long)blockIdx.x * 4 + wv) * 16;
    const long r = row0 + rr;

    float* out_q = out;
    float* out_i = out + (size_t)M * ZD;   // holds hn (from prep_h)
    float* out_l = out_i + M;              // receives besti
    const float INF = __builtin_inff();

    const float* rec = out_q + (size_t)r * ZD;
    const int cnt = (int)rec[0];           // 4 lanes of a row share the line
    const float hn = out_i[r];

    int besti = 0;
    if (cnt == 1) {
        besti = (int)rec[1];
    } else if (cnt >= 2) {
        float bd = INF; int bi = 0x7FFFFFFF;
        const float* hrow = h + (size_t)r * ZD;
        const int j0 = c, j1 = c + 4;
        const bool v0 = (j0 < cnt), v1 = (j1 < cnt);
        if (v0 && v1) {
            const int i0 = (int)rec[1 + j0], i1 = (int)rec[1 + j1];
            float2 dd = exact_d2(hrow, emb + (size_t)i0 * ZD, emb + (size_t)i1 * ZD,
                                 hn, en[i0], en[i1]);
            bd = dd.x; bi = i0;
            if (dd.y < bd || (dd.y == bd && i1 < bi)) { bd = dd.y; bi = i1; }
        } else if (v0) {
            const int i0 = (int)rec[1 + j0];
            bd = exact_d(hrow, emb + (size_t)i0 * ZD, hn, en[i0]);
            bi = i0;
        }
        #pragma unroll
        for (int o = 1; o < 4; o <<= 1) {   // reduce across the row's 4 lanes
            float ov = __shfl_xor(bd, o, 64);
            int   oi = __shfl_xor(bi, o, 64);
            if (ov < bd || (ov == bd && oi < bi)) { bd = ov; bi = oi; }
        }
        besti = bi;
    }

    // exhaustive rows (cnt<0, ultra-rare): whole-wave, lane-parallel entries
    unsigned long long exm = __ballot(cnt < 0) & 0x1111111111111111ull; // c==0 bits
    while (exm) {
        const int bit = (int)(__ffsll(exm) - 1);
        exm &= exm - 1;
        const int xr = bit >> 2;
        const long row = row0 + xr;
        const float hnx = out_i[row];
        const float* hrowx = h + (size_t)row * ZD;
        float bd = INF;
        int   bi = 0x7FFFFFFF;
        for (int e = lane; e < NE; e += 64) {
            float dx = exact_d(hrowx, emb + (size_t)e * ZD, hnx, en[e]);
            if (dx < bd || (dx == bd && e < bi)) { bd = dx; bi = e; }
        }
        #pragma unroll
        for (int o = 1; o < 64; o <<= 1) {
            float ov = __shfl_xor(bd, o, 64);
            int   oi = __shfl_xor(bi, o, 64);
            if (ov < bd || (ov == bd && oi < bi)) { bd = ov; bi = oi; }
        }
        if (rr == xr) besti = bi;
    }

    if (c == 0) out_l[r] = (float)besti;
}

// ---------------------------------------------------------------------------
// K2b stream: pure-bandwidth epilogue at full TLP (8192 blocks, 32768 waves).
// Reads besti from out_l[r] (same-wave read precedes the lg==0 overwrite),
// then R1's byte-exact epilogue: out_q / out_i / out_l.
// ---------------------------------------------------------------------------
__global__ __launch_bounds__(256) void vq_stream(const float* __restrict__ h,
                                                 const float* __restrict__ emb,
                                                 float* out, int M) {
    const int t    = threadIdx.x;
    const int lane = t & 63;
    const int wv   = t >> 6;      // 0..3
    const int g    = lane >> 4;   // 0..3
    const int lg   = lane & 15;
    const long r = (long)blockIdx.x * 16 + wv * 4 + g;

    float* out_q = out;
    float* out_i = out + (size_t)M * ZD;
    float* out_l = out_i + M;

    const int b = (int)out_l[r];
    const float* hrow = h + (size_t)r * ZD;
    const float* erow = emb + (size_t)b * ZD;
    float csum = 0.0f;
    #pragma unroll
    for (int q4 = 0; q4 < 4; ++q4) {
        int k = lg * 16 + q4 * 4;
        float4 hv = *(const float4*)(hrow + k);
        float4 ev = *(const float4*)(erow + k);
        float dx = __fsub_rn(ev.x, hv.x);
        float dy = __fsub_rn(ev.y, hv.y);
        float dz = __fsub_rn(ev.z, hv.z);
        float dw = __fsub_rn(ev.w, hv.w);
        float4 o;
        o.x = __fadd_rn(hv.x, dx);
        o.y = __fadd_rn(hv.y, dy);
        o.z = __fadd_rn(hv.z, dz);
        o.w = __fadd_rn(hv.w, dw);
        *(float4*)(out_q + (size_t)r * ZD + k) = o;
        csum = fmaf(dx, dx, csum);
        csum = fmaf(dy, dy, csum);
        csum = fmaf(dz, dz, csum);
        csum = fmaf(dw, dw, csum);
    }
    #pragma unroll
    for (int o2 = 1; o2 < 16; o2 <<= 1) csum += __shfl_xor(csum, o2, 64);
    if (lg == 0) {
        float cmean = csum * (1.0f / 256.0f);
        out_i[r] = (float)b;
        out_l[r] = __fadd_rn(__fmul_rn(cmean, 0.1f), __fmul_rn(cmean, 0.2f));
    }
}

extern "C" void kernel_launch(void* const* d_in, const int* in_sizes, int n_in,
                              void* d_out, int out_size, void* d_ws, size_t ws_size,
                              hipStream_t stream) {
    const float* h   = (const float*)d_in[0];
    const float* emb = (const float*)d_in[1];
    const int M = in_sizes[0] / ZD;   // 131072

    unsigned char* ebB = (unsigned char*)d_ws;               // 512 KB bf16 swizzled
    float* en = (float*)(ebB + (size_t)NP * ZD * 2);         // 4 KB

    float* out = (float*)d_out;
    unsigned short* hb = (unsigned short*)d_out;             // bf16 h in out_q region
    float* hn = out + (size_t)M * ZD;                        // hn in out_i region

    prep_e<<<NP / 64, 64, 0, stream>>>(emb, ebB, en);
    prep_h<<<M / 64, 256, 0, stream>>>(h, hb, hn);

    const size_t lds_bytes = 131072 + 256 * sizeof(float);
    (void)hipFuncSetAttribute((const void*)vq_main,
                              hipFuncAttributeMaxDynamicSharedMemorySize,
                              (int)lds_bytes);
    vq_main<<<M / 256, 1024, lds_bytes, stream>>>(h, emb, ebB, en, out, M);
    vq_resolve<<<M / 64, 256, 0, stream>>>(h, emb, en, out, M);   // 16 rows/wave
    vq_stream<<<M / 16, 256, 0, stream>>>(h, emb, out, M);        // 4 rows/wave
}